// Round 12
// baseline (1083.575 us; speedup 1.0000x reference)
//
#include <hip/hip_runtime.h>
#include <hip/hip_bf16.h>

#define N_USERS 100000
#define N_ITEMS 50000
#define N_TOTAL 150000
#define NNZ     4000000
#define ALPHA_F 0.8f
#define ELL_CAP 128

#define G_SCAT 1024
#define G_COPY 128
#define G_PRE  (G_SCAT + G_COPY)
#define G_GEMM 3125           // N_ITEMS / 16 exactly
#define NC_ALL 18             // 16 img chunks (K=256 each) + 2 txt chunks (K=192 each)

typedef __attribute__((ext_vector_type(8))) short bf16x8;
typedef __attribute__((ext_vector_type(4))) float f32x4;

static __device__ __forceinline__ short f2bf(float f) {
    unsigned u = __builtin_bit_cast(unsigned, f);
    unsigned r = (u + 0x7fff + ((u >> 16) & 1)) >> 16;   // RTNE
    return (short)r;
}
static __device__ __forceinline__ unsigned pack_bf2(float a, float b) {
    return (unsigned)(unsigned short)f2bf(a) | ((unsigned)(unsigned short)f2bf(b) << 16);
}
static __device__ __forceinline__ float bf_lo(unsigned u) { return __uint_as_float(u << 16); }
static __device__ __forceinline__ float bf_hi(unsigned u) { return __uint_as_float(u & 0xFFFF0000u); }

// ---------------------------------------------------------------- prep: zero cnt + W transposes

__global__ __launch_bounds__(256) void prep_kernel(const float* __restrict__ Wimg,
                                                   const float* __restrict__ Wtxt,
                                                   int* __restrict__ cnt,
                                                   short* __restrict__ Wti,
                                                   short* __restrict__ Wtt) {
    const int T0 = N_TOTAL;
    const int T1 = T0 + 4096 * 64;
    const int T2 = T1 + 384 * 64;
    int i = blockIdx.x * 256 + threadIdx.x;
    int stride = gridDim.x * 256;
    for (; i < T2; i += stride) {
        if (i < T0) {
            cnt[i] = 0;
        } else if (i < T1) {
            int idx = i - T0; int k = idx >> 6, n = idx & 63;
            Wti[(size_t)n * 4096 + k] = f2bf(Wimg[(size_t)k * 64 + n]);
        } else {
            int idx = i - T1; int k = idx >> 6, n = idx & 63;
            Wtt[(size_t)n * 384 + k] = f2bf(Wtxt[(size_t)k * 64 + n]);
        }
    }
}

// ---------------------------------------------------------------- mega kernel
// [0, G_SCAT):      ELL scatter with 4-way atomic ILP
// [G_SCAT, G_PRE):  user pref -> bf16 mirror
// [G_PRE, ...):     item GEMM: 16 rows/block; A reg-staged (T14: issue-early,
//                   ds_write-late) through the VECTOR path (not LDS-DMA);
//                   32KB LDS double buffer; B direct from L2-resident Wt.

__global__ __launch_bounds__(256, 4) void mega_kernel(
        const float* __restrict__ Aimg, const float* __restrict__ Atxt,
        const short* __restrict__ Wti, const short* __restrict__ Wtt,
        const float* __restrict__ bimg, const float* __restrict__ btxt,
        unsigned* __restrict__ egob,
        const int* __restrict__ rows, const int* __restrict__ cols,
        const float* __restrict__ vals, int* __restrict__ cnt, int2* __restrict__ ell,
        const float* __restrict__ img_pref, const float* __restrict__ txt_pref) {
    __shared__ __align__(16) char atile[32768];   // two 16KB halves
    int b = blockIdx.x;
    int t = threadIdx.x;
    int wave = t >> 6, lane = t & 63;

    if (b < G_SCAT) {
        const int stride = G_SCAT * 256;
        int i = b * 256 + t;
        for (; i + 3 * stride < NNZ; i += 4 * stride) {
            int r0 = rows[i],            c0 = cols[i];            float v0 = vals[i];
            int r1 = rows[i + stride],   c1 = cols[i + stride];   float v1 = vals[i + stride];
            int r2 = rows[i + 2*stride], c2 = cols[i + 2*stride]; float v2 = vals[i + 2*stride];
            int r3 = rows[i + 3*stride], c3 = cols[i + 3*stride]; float v3 = vals[i + 3*stride];
            int p0 = atomicAdd(&cnt[r0], 1);
            int p1 = atomicAdd(&cnt[r1], 1);
            int p2 = atomicAdd(&cnt[r2], 1);
            int p3 = atomicAdd(&cnt[r3], 1);
            if (p0 < ELL_CAP) ell[(size_t)r0 * ELL_CAP + p0] = make_int2(c0, __float_as_int(v0));
            if (p1 < ELL_CAP) ell[(size_t)r1 * ELL_CAP + p1] = make_int2(c1, __float_as_int(v1));
            if (p2 < ELL_CAP) ell[(size_t)r2 * ELL_CAP + p2] = make_int2(c2, __float_as_int(v2));
            if (p3 < ELL_CAP) ell[(size_t)r3 * ELL_CAP + p3] = make_int2(c3, __float_as_int(v3));
        }
        for (; i < NNZ; i += stride) {
            int r = rows[i];
            int p = atomicAdd(&cnt[r], 1);
            if (p < ELL_CAP)
                ell[(size_t)r * ELL_CAP + p] = make_int2(cols[i], __float_as_int(vals[i]));
        }
        return;
    }
    if (b < G_PRE) {
        int idx = (b - G_SCAT) * 256 + t;
        int stride = G_COPY * 256;
        for (; idx < N_USERS * 16; idx += stride) {
            int row = idx >> 4, w4 = (idx & 15) << 2;
            float4 iv = *reinterpret_cast<const float4*>(&img_pref[(size_t)row * 64 + w4]);
            float4 tv = *reinterpret_cast<const float4*>(&txt_pref[(size_t)row * 64 + w4]);
            uint4 m;
            m.x = pack_bf2(iv.x, tv.x); m.y = pack_bf2(iv.y, tv.y);
            m.z = pack_bf2(iv.z, tv.z); m.w = pack_bf2(iv.w, tv.w);
            *reinterpret_cast<uint4*>(&egob[(size_t)row * 64 + w4]) = m;
        }
        return;
    }

    // ---------------- GEMM ----------------
    const int blk = b - G_PRE;
    const int row0 = blk * 16;
    const int col = lane & 15, kb = lane >> 4;

    f32x4 s0, s1, s2, s3;   // staging regs (load early, ds_write late)

    // img chunk ci: 16 rows x 1KB; load j reads 1KB contiguous of row j*4+wave
    auto ld_img = [&](int ci) {
        const char* base = (const char*)Aimg + (size_t)row0 * 16384 + ci * 1024 + lane * 16;
        s0 = *(const f32x4*)(base + (size_t)(0 * 4 + wave) * 16384);
        s1 = *(const f32x4*)(base + (size_t)(1 * 4 + wave) * 16384);
        s2 = *(const f32x4*)(base + (size_t)(2 * 4 + wave) * 16384);
        s3 = *(const f32x4*)(base + (size_t)(3 * 4 + wave) * 16384);
        __builtin_amdgcn_sched_barrier(0);
    };
    auto wr_img = [&](int bi) {
        char* d = (char*)atile + bi * 16384;
        int r0r = 0 * 4 + wave, r1r = 1 * 4 + wave, r2r = 2 * 4 + wave, r3r = 3 * 4 + wave;
        *(f32x4*)(d + r0r * 1024 + ((lane * 16) ^ ((r0r & 7) << 4))) = s0;
        *(f32x4*)(d + r1r * 1024 + ((lane * 16) ^ ((r1r & 7) << 4))) = s1;
        *(f32x4*)(d + r2r * 1024 + ((lane * 16) ^ ((r2r & 7) << 4))) = s2;
        *(f32x4*)(d + r3r * 1024 + ((lane * 16) ^ ((r3r & 7) << 4))) = s3;
    };
    // txt chunk ci (0/1): 16 rows x 768B; thread t covers 48B of row t>>4
    auto ld_txt = [&](int ci) {
        int r = t >> 4, po = (t & 15) * 48;
        const char* base = (const char*)Atxt + (size_t)(row0 + r) * 1536 + ci * 768 + po;
        s0 = *(const f32x4*)(base);
        s1 = *(const f32x4*)(base + 16);
        s2 = *(const f32x4*)(base + 32);
        __builtin_amdgcn_sched_barrier(0);
    };
    auto wr_txt = [&](int bi) {
        int r = t >> 4, po = (t & 15) * 48, sw = (r & 7) << 4;
        char* d = (char*)atile + bi * 16384 + r * 1024;
        *(f32x4*)(d + ((po     ) ^ sw)) = s0;
        *(f32x4*)(d + ((po + 16) ^ sw)) = s1;
        *(f32x4*)(d + ((po + 32) ^ sw)) = s2;
    };
    auto ld = [&](int ci) { if (ci < 16) ld_img(ci); else ld_txt(ci - 16); };
    auto wr = [&](int ci, int bi) { if (ci < 16) wr_img(bi); else wr_txt(bi); };

    // compute nks k-steps from staged chunk; B direct from global (L2-hot)
    auto comp = [&](const char* base, const short* Wt, int K, int kabs, int nks, f32x4& acc) {
        const int row = col;
        const int swz = (row & 7) << 4;
        const char* ab = base + row * 1024;
        const short* wp = Wt + (size_t)(16 * wave + col) * K + kabs + kb * 8;
        for (int ks = 0; ks < nks; ++ks) {
            int lg = kb * 32 + ks * 128;
            float4 a0 = *(const float4*)(ab + (lg ^ swz));
            float4 a1 = *(const float4*)(ab + ((lg + 16) ^ swz));
            bf16x8 af;
            af[0]=f2bf(a0.x); af[1]=f2bf(a0.y); af[2]=f2bf(a0.z); af[3]=f2bf(a0.w);
            af[4]=f2bf(a1.x); af[5]=f2bf(a1.y); af[6]=f2bf(a1.z); af[7]=f2bf(a1.w);
            bf16x8 bfr = *(const bf16x8*)(wp + ks * 32);
            acc = __builtin_amdgcn_mfma_f32_16x16x32_bf16(af, bfr, acc, 0, 0, 0);
        }
    };

    f32x4 ai = {0.f,0.f,0.f,0.f}, at4 = {0.f,0.f,0.f,0.f};

    ld(0);
    wr(0, 0);                 // compiler inserts vmcnt before first reg use
    __syncthreads();
    ld(1);
    for (int ci = 0; ci < NC_ALL; ++ci) {
        int bi = ci & 1;
        if (ci < 16) comp((const char*)atile + bi * 16384, Wti, 4096, ci * 256, 8, ai);
        else         comp((const char*)atile + bi * 16384, Wtt, 384, (ci - 16) * 192, 6, at4);
        __syncthreads();                       // buf[bi^1] free; drains in-flight loads
        if (ci + 1 < NC_ALL) {
            wr(ci + 1, bi ^ 1);
            if (ci + 2 < NC_ALL) ld(ci + 2);   // issue next loads early (T14)
            __syncthreads();                   // writes visible before next compute
        }
    }

    // ---------------- bias + cross-wave L2 norm + mirror store ----------------
    float bv_i = bimg[16 * wave + col];
    float bv_t = btxt[16 * wave + col];
    float ssi[4], sst[4];
    #pragma unroll
    for (int i = 0; i < 4; ++i) {
        ai[i] += bv_i; at4[i] += bv_t;
        ssi[i] = ai[i] * ai[i];
        sst[i] = at4[i] * at4[i];
    }
    #pragma unroll
    for (int off = 1; off < 16; off <<= 1) {
        #pragma unroll
        for (int i = 0; i < 4; ++i) {
            ssi[i] += __shfl_xor(ssi[i], off, 64);
            sst[i] += __shfl_xor(sst[i], off, 64);
        }
    }
    float* S = (float*)atile;          // [2][4 waves][16 rows]
    __syncthreads();
    if (col == 0) {
        #pragma unroll
        for (int i = 0; i < 4; ++i) {
            S[wave * 16 + kb * 4 + i]      = ssi[i];
            S[64 + wave * 16 + kb * 4 + i] = sst[i];
        }
    }
    __syncthreads();
    unsigned* egob_items = egob + (size_t)N_USERS * 64;
    #pragma unroll
    for (int i = 0; i < 4; ++i) {
        int r = kb * 4 + i;
        float ti = S[r] + S[16 + r] + S[32 + r] + S[48 + r];
        float tt = S[64 + r] + S[80 + r] + S[96 + r] + S[112 + r];
        float rni = 1.0f / fmaxf(sqrtf(ti), 1e-12f);
        float rnt = 1.0f / fmaxf(sqrtf(tt), 1e-12f);
        egob_items[(size_t)(row0 + r) * 64 + 16 * wave + col] =
            pack_bf2(ai[i] * rni, at4[i] * rnt);
    }
}

// ---------------------------------------------------------------- SpMM layer 1 + fused sort

__global__ __launch_bounds__(256) void spmm_sort_kernel(
        const int* __restrict__ cnt, int2* __restrict__ ell,
        const unsigned* __restrict__ xb, unsigned* __restrict__ outb) {
    __shared__ __align__(16) int2 srt[4][ELL_CAP];
    int wid = threadIdx.x >> 6, lane = threadIdx.x & 63;
    int row = blockIdx.x * 4 + wid;
    bool valid = row < N_TOTAL;
    int deg = 0;
    int2* base = nullptr;
    int2 e0 = make_int2(0x7FFFFFFF, 0), e1 = e0;
    if (valid) {
        deg = min(cnt[row], ELL_CAP);
        base = ell + (size_t)row * ELL_CAP;
        if (lane < deg)      e0 = base[lane];
        if (lane + 64 < deg) e1 = base[lane + 64];
    }
    #pragma unroll
    for (int k = 2; k <= 128; k <<= 1) {
        #pragma unroll
        for (int j = 64; j >= 1; j >>= 1) {
            if (j >= k) continue;
            if (j == 64) {
                if (e0.x > e1.x) { int2 tmp = e0; e0 = e1; e1 = tmp; }
            } else {
                int2 p0, p1;
                p0.x = __shfl_xor(e0.x, j, 64); p0.y = __shfl_xor(e0.y, j, 64);
                p1.x = __shfl_xor(e1.x, j, 64); p1.y = __shfl_xor(e1.y, j, 64);
                bool up0 = ((lane & k) == 0);
                bool up1 = (((lane + 64) & k) == 0);
                bool lo0 = ((lane & j) == 0);
                bool keepmin0 = (up0 == lo0);
                bool keepmin1 = (up1 == lo0);
                if (keepmin0 ? (e0.x > p0.x) : (e0.x < p0.x)) e0 = p0;
                if (keepmin1 ? (e1.x > p1.x) : (e1.x < p1.x)) e1 = p1;
            }
        }
    }
    if (valid) {
        if (lane < deg)      base[lane]      = e0;
        if (lane + 64 < deg) base[lane + 64] = e1;
    }
    srt[wid][lane] = e0;
    srt[wid][lane + 64] = e1;
    __syncthreads();
    if (!valid) return;
    unsigned sw = xb[(size_t)row * 64 + lane];
    float2 acc;
    acc.x = ALPHA_F * bf_lo(sw);
    acc.y = ALPHA_F * bf_hi(sw);
    const int2* s = srt[wid];
    int i = 0;
    for (; i + 8 <= deg; i += 8) {
        int4 p0 = *reinterpret_cast<const int4*>(s + i);
        int4 p1 = *reinterpret_cast<const int4*>(s + i + 2);
        int4 p2 = *reinterpret_cast<const int4*>(s + i + 4);
        int4 p3 = *reinterpret_cast<const int4*>(s + i + 6);
        unsigned g0 = xb[(size_t)p0.x * 64 + lane];
        unsigned g1 = xb[(size_t)p0.z * 64 + lane];
        unsigned g2 = xb[(size_t)p1.x * 64 + lane];
        unsigned g3 = xb[(size_t)p1.z * 64 + lane];
        unsigned g4 = xb[(size_t)p2.x * 64 + lane];
        unsigned g5 = xb[(size_t)p2.z * 64 + lane];
        unsigned g6 = xb[(size_t)p3.x * 64 + lane];
        unsigned g7 = xb[(size_t)p3.z * 64 + lane];
        float v0 = __int_as_float(p0.y), v1 = __int_as_float(p0.w);
        float v2 = __int_as_float(p1.y), v3 = __int_as_float(p1.w);
        float v4 = __int_as_float(p2.y), v5 = __int_as_float(p2.w);
        float v6 = __int_as_float(p3.y), v7 = __int_as_float(p3.w);
        acc.x = fmaf(v0, bf_lo(g0), acc.x); acc.y = fmaf(v0, bf_hi(g0), acc.y);
        acc.x = fmaf(v1, bf_lo(g1), acc.x); acc.y = fmaf(v1, bf_hi(g1), acc.y);
        acc.x = fmaf(v2, bf_lo(g2), acc.x); acc.y = fmaf(v2, bf_hi(g2), acc.y);
        acc.x = fmaf(v3, bf_lo(g3), acc.x); acc.y = fmaf(v3, bf_hi(g3), acc.y);
        acc.x = fmaf(v4, bf_lo(g4), acc.x); acc.y = fmaf(v4, bf_hi(g4), acc.y);
        acc.x = fmaf(v5, bf_lo(g5), acc.x); acc.y = fmaf(v5, bf_hi(g5), acc.y);
        acc.x = fmaf(v6, bf_lo(g6), acc.x); acc.y = fmaf(v6, bf_hi(g6), acc.y);
        acc.x = fmaf(v7, bf_lo(g7), acc.x); acc.y = fmaf(v7, bf_hi(g7), acc.y);
    }
    for (; i < deg; ++i) {
        int2 c = s[i];
        float v = __int_as_float(c.y);
        unsigned g = xb[(size_t)c.x * 64 + lane];
        acc.x = fmaf(v, bf_lo(g), acc.x);
        acc.y = fmaf(v, bf_hi(g), acc.y);
    }
    outb[(size_t)row * 64 + lane] = pack_bf2(acc.x, acc.y);
}

// ---------------------------------------------------------------- SpMM layers 2-3

__global__ __launch_bounds__(256) void spmm_kernel(
        const int* __restrict__ cnt, const int2* __restrict__ ell,
        const unsigned* __restrict__ xb,
        float* __restrict__ out32, unsigned* __restrict__ outb) {
    int row = blockIdx.x * 4 + (threadIdx.x >> 6);
    if (row >= N_TOTAL) return;
    int lane = threadIdx.x & 63;
    unsigned sw = xb[(size_t)row * 64 + lane];
    float2 acc;
    acc.x = ALPHA_F * bf_lo(sw);
    acc.y = ALPHA_F * bf_hi(sw);
    int deg = min(cnt[row], ELL_CAP);
    const int2* base = ell + (size_t)row * ELL_CAP;
    int i = 0;
    for (; i + 8 <= deg; i += 8) {
        int4 p0 = *reinterpret_cast<const int4*>(base + i);
        int4 p1 = *reinterpret_cast<const int4*>(base + i + 2);
        int4 p2 = *reinterpret_cast<const int4*>(base + i + 4);
        int4 p3 = *reinterpret_cast<const int4*>(base + i + 6);
        unsigned g0 = xb[(size_t)p0.x * 64 + lane];
        unsigned g1 = xb[(size_t)p0.z * 64 + lane];
        unsigned g2 = xb[(size_t)p1.x * 64 + lane];
        unsigned g3 = xb[(size_t)p1.z * 64 + lane];
        unsigned g4 = xb[(size_t)p2.x * 64 + lane];
        unsigned g5 = xb[(size_t)p2.z * 64 + lane];
        unsigned g6 = xb[(size_t)p3.x * 64 + lane];
        unsigned g7 = xb[(size_t)p3.z * 64 + lane];
        float v0 = __int_as_float(p0.y), v1 = __int_as_float(p0.w);
        float v2 = __int_as_float(p1.y), v3 = __int_as_float(p1.w);
        float v4 = __int_as_float(p2.y), v5 = __int_as_float(p2.w);
        float v6 = __int_as_float(p3.y), v7 = __int_as_float(p3.w);
        acc.x = fmaf(v0, bf_lo(g0), acc.x); acc.y = fmaf(v0, bf_hi(g0), acc.y);
        acc.x = fmaf(v1, bf_lo(g1), acc.x); acc.y = fmaf(v1, bf_hi(g1), acc.y);
        acc.x = fmaf(v2, bf_lo(g2), acc.x); acc.y = fmaf(v2, bf_hi(g2), acc.y);
        acc.x = fmaf(v3, bf_lo(g3), acc.x); acc.y = fmaf(v3, bf_hi(g3), acc.y);
        acc.x = fmaf(v4, bf_lo(g4), acc.x); acc.y = fmaf(v4, bf_hi(g4), acc.y);
        acc.x = fmaf(v5, bf_lo(g5), acc.x); acc.y = fmaf(v5, bf_hi(g5), acc.y);
        acc.x = fmaf(v6, bf_lo(g6), acc.x); acc.y = fmaf(v6, bf_hi(g6), acc.y);
        acc.x = fmaf(v7, bf_lo(g7), acc.x); acc.y = fmaf(v7, bf_hi(g7), acc.y);
    }
    for (; i < deg; ++i) {
        int2 c = base[i];
        float v = __int_as_float(c.y);
        unsigned g = xb[(size_t)c.x * 64 + lane];
        acc.x = fmaf(v, bf_lo(g), acc.x);
        acc.y = fmaf(v, bf_hi(g), acc.y);
    }
    if (out32) {
        out32[(size_t)row * 128 + lane] = acc.x;
        out32[(size_t)row * 128 + 64 + lane] = acc.y;
    }
    if (outb)
        outb[(size_t)row * 64 + lane] = pack_bf2(acc.x, acc.y);
}

// ---------------------------------------------------------------- launch

extern "C" void kernel_launch(void* const* d_in, const int* in_sizes, int n_in,
                              void* d_out, int out_size, void* d_ws, size_t ws_size,
                              hipStream_t stream) {
    const float* image_feats = (const float*)d_in[0];
    const float* text_feats  = (const float*)d_in[1];
    const float* image_pref  = (const float*)d_in[2];
    const float* text_pref   = (const float*)d_in[3];
    const float* W_img       = (const float*)d_in[4];
    const float* b_img       = (const float*)d_in[5];
    const float* W_txt       = (const float*)d_in[6];
    const float* b_txt       = (const float*)d_in[7];
    const float* adj_vals    = (const float*)d_in[8];
    const int*   adj_rows    = (const int*)d_in[9];
    const int*   adj_cols    = (const int*)d_in[10];

    float* out = (float*)d_out;                          // [150000*128]

    char* ws = (char*)d_ws;
    size_t off = 0;
    auto alloc = [&](size_t bytes) { char* p = ws + off; off += (bytes + 255) & ~size_t(255); return p; };
    int*      cnt    = (int*)     alloc(N_TOTAL * sizeof(int));
    int2*     ell    = (int2*)    alloc((size_t)N_TOTAL * ELL_CAP * sizeof(int2));
    unsigned* m0     = (unsigned*)alloc((size_t)N_TOTAL * 64 * sizeof(unsigned));
    unsigned* m1     = (unsigned*)alloc((size_t)N_TOTAL * 64 * sizeof(unsigned));
    short*    Wt_img = (short*)   alloc((size_t)64 * 4096 * sizeof(short));
    short*    Wt_txt = (short*)   alloc((size_t)64 * 384 * sizeof(short));
    (void)ws_size; (void)out_size; (void)n_in; (void)in_sizes;

    // --- prep: zero cnt + bf16 W transposes ---
    prep_kernel<<<512, 256, 0, stream>>>(W_img, W_txt, cnt, Wt_img, Wt_txt);

    // --- mega: scatter || copy || GEMM ---
    mega_kernel<<<G_PRE + G_GEMM, 256, 0, stream>>>(
        image_feats, text_feats, Wt_img, Wt_txt, b_img, b_txt, m0,
        adj_rows, adj_cols, adj_vals, cnt, ell, image_pref, text_pref);

    // --- layer 1 (+ canonical in-kernel sort), then layers 2-3 ---
    const int ROW_GRID = (N_TOTAL + 3) / 4;
    spmm_sort_kernel<<<ROW_GRID, 256, 0, stream>>>(cnt, ell, m0, m1);
    spmm_kernel<<<ROW_GRID, 256, 0, stream>>>(cnt, ell, m1, nullptr, m0);
    spmm_kernel<<<ROW_GRID, 256, 0, stream>>>(cnt, ell, m0, out, nullptr);
}

// Round 13
// 1024.769 us; speedup vs baseline: 1.0574x; 1.0574x over previous
//
#include <hip/hip_runtime.h>
#include <hip/hip_bf16.h>

#define N_USERS 100000
#define N_ITEMS 50000
#define N_TOTAL 150000
#define NNZ     4000000
#define ALPHA_F 0.8f
#define ELL_CAP 128

#define C_COPY 512
#define C_SCAT 1024
#define G_GEMM 3125           // N_ITEMS / 16 exactly
#define NC_IMG 32             // img chunks of K=128
#define NC_ALL 35             // + 3 txt chunks of K=128

typedef __attribute__((ext_vector_type(8))) short bf16x8;
typedef __attribute__((ext_vector_type(4))) float f32x4;

static __device__ __forceinline__ short f2bf(float f) {
    unsigned u = __builtin_bit_cast(unsigned, f);
    unsigned r = (u + 0x7fff + ((u >> 16) & 1)) >> 16;   // RTNE
    return (short)r;
}
static __device__ __forceinline__ unsigned pack_bf2(float a, float b) {
    return (unsigned)(unsigned short)f2bf(a) | ((unsigned)(unsigned short)f2bf(b) << 16);
}
static __device__ __forceinline__ float bf_lo(unsigned u) { return __uint_as_float(u << 16); }
static __device__ __forceinline__ float bf_hi(unsigned u) { return __uint_as_float(u & 0xFFFF0000u); }

static __device__ __forceinline__ void gload_lds16(const void* src, void* dst) {
    __builtin_amdgcn_global_load_lds(
        (const __attribute__((address_space(1))) unsigned*)src,
        (__attribute__((address_space(3))) unsigned*)dst, 16, 0, 0);
}

// ---------------------------------------------------------------- prep
// zero cnt + build tiled/swizzled bf16 B: WtT[c][n][k'] with byte
// (k'*2) ^ ((n&7)<<4); chunk = 16KB. img: 32 chunks; txt: 3 chunks.

__global__ __launch_bounds__(256) void prep_kernel(const float* __restrict__ Wimg,
                                                   const float* __restrict__ Wtxt,
                                                   int* __restrict__ cnt,
                                                   char* __restrict__ WtiT,
                                                   char* __restrict__ WttT) {
    const int T0 = N_TOTAL;
    const int T1 = T0 + 4096 * 64;
    const int T2 = T1 + 384 * 64;
    int i = blockIdx.x * 256 + threadIdx.x;
    int stride = gridDim.x * 256;
    for (; i < T2; i += stride) {
        if (i < T0) {
            cnt[i] = 0;
        } else if (i < T1) {
            int idx = i - T0; int k = idx >> 6, n = idx & 63;
            int c = k >> 7, kk = k & 127;
            *(short*)(WtiT + c * 16384 + n * 256 + ((kk * 2) ^ ((n & 7) << 4)))
                = f2bf(Wimg[(size_t)k * 64 + n]);
        } else {
            int idx = i - T1; int k = idx >> 6, n = idx & 63;
            int c = k >> 7, kk = k & 127;
            *(short*)(WttT + c * 16384 + n * 256 + ((kk * 2) ^ ((n & 7) << 4)))
                = f2bf(Wtxt[(size_t)k * 64 + n]);
        }
    }
}

// ---------------------------------------------------------------- GEMM
// 16 rows/block (3125 blocks). Per chunk (K=128): stage A f32 8KB (2 insts/thr,
// pre-swizzled src, linear LDS dst) + B bf16 16KB (4 insts/thr, pre-tiled).
// comp = pure LDS + MFMA (NO vmem) -> counted vmcnt(6) prefetch survives.

__global__ __launch_bounds__(256, 3) void gemm_kernel(
        const float* __restrict__ Aimg, const float* __restrict__ Atxt,
        const char* __restrict__ WtiT, const char* __restrict__ WttT,
        const float* __restrict__ bimg, const float* __restrict__ btxt,
        unsigned* __restrict__ egob_items) {
    __shared__ __align__(16) char abuf[2][8192];
    __shared__ __align__(16) char bbuf[2][16384];
    const int t = threadIdx.x;
    const int wave = t >> 6, lane = t & 63;
    const int col = lane & 15, kb = lane >> 4;
    const int row0 = blockIdx.x * 16;

    auto stage = [&](int ci, int bi) {
        const float* A; size_t rowbytes; const char* BT; int cc;
        if (ci < NC_IMG) { A = Aimg; rowbytes = 16384; BT = WtiT; cc = ci; }
        else             { A = Atxt; rowbytes = 1536;  BT = WttT; cc = ci - NC_IMG; }
        // A: 2 calls; call q: lane -> row (q*4+wave)*2 + (lane>>5), 16B slot lane&31
        #pragma unroll
        for (int q = 0; q < 2; ++q) {
            int r = (q * 4 + wave) * 2 + (lane >> 5);
            int so = ((lane & 31) * 16) ^ ((r & 7) << 4);
            const char* src = (const char*)A + (size_t)(row0 + r) * rowbytes + cc * 512 + so;
            char* dst = abuf[bi] + (q * 4 + wave) * 1024 + lane * 16;
            gload_lds16(src, dst);
        }
        // B: 4 calls, fully linear (tiled layout already swizzled)
        #pragma unroll
        for (int q = 0; q < 4; ++q) {
            int off = (q * 4 + wave) * 1024 + lane * 16;
            gload_lds16(BT + (size_t)cc * 16384 + off, bbuf[bi] + off);
        }
    };

    // comp: 4 k-steps; A-frag row=col (f32, swizzled), B-frag n=16*wave+col
    auto comp = [&](int bi, f32x4& acc) {
        const int r = col;
        const int aswz = (r & 7) << 4;
        const char* ab = abuf[bi] + r * 512;
        const int n = 16 * wave + col;
        const char* bb = bbuf[bi] + n * 256;
        const int bswz = (n & 7) << 4;
        #pragma unroll
        for (int ks = 0; ks < 4; ++ks) {
            int la = ks * 128 + kb * 32;
            float4 a0 = *(const float4*)(ab + (la ^ aswz));
            float4 a1 = *(const float4*)(ab + ((la + 16) ^ aswz));
            bf16x8 af;
            af[0]=f2bf(a0.x); af[1]=f2bf(a0.y); af[2]=f2bf(a0.z); af[3]=f2bf(a0.w);
            af[4]=f2bf(a1.x); af[5]=f2bf(a1.y); af[6]=f2bf(a1.z); af[7]=f2bf(a1.w);
            bf16x8 bf = *(const bf16x8*)(bb + ((ks * 64 + kb * 16) ^ bswz));
            acc = __builtin_amdgcn_mfma_f32_16x16x32_bf16(af, bf, acc, 0, 0, 0);
        }
    };

    f32x4 ai = {0.f,0.f,0.f,0.f}, at4 = {0.f,0.f,0.f,0.f};

    stage(0, 0);
    for (int ci = 0; ci < NC_ALL; ++ci) {
        int bi = ci & 1;
        if (ci + 1 < NC_ALL) {
            stage(ci + 1, bi ^ 1);
            asm volatile("s_waitcnt vmcnt(6)" ::: "memory");   // stage(ci) done; next in flight
        } else {
            asm volatile("s_waitcnt vmcnt(0)" ::: "memory");
        }
        __builtin_amdgcn_s_barrier();
        __builtin_amdgcn_sched_barrier(0);
        if (ci < NC_IMG) comp(bi, ai);
        else             comp(bi, at4);
        __builtin_amdgcn_sched_barrier(0);
        __builtin_amdgcn_s_barrier();
    }

    // ---------------- bias + cross-wave L2 norm + mirror store ----------------
    float bv_i = bimg[16 * wave + col];
    float bv_t = btxt[16 * wave + col];
    float ssi[4], sst[4];
    #pragma unroll
    for (int i = 0; i < 4; ++i) {
        ai[i] += bv_i; at4[i] += bv_t;
        ssi[i] = ai[i] * ai[i];
        sst[i] = at4[i] * at4[i];
    }
    #pragma unroll
    for (int off = 1; off < 16; off <<= 1) {
        #pragma unroll
        for (int i = 0; i < 4; ++i) {
            ssi[i] += __shfl_xor(ssi[i], off, 64);
            sst[i] += __shfl_xor(sst[i], off, 64);
        }
    }
    float* S = (float*)abuf;           // [2][4 waves][16 rows]
    __syncthreads();
    if (col == 0) {
        #pragma unroll
        for (int i = 0; i < 4; ++i) {
            S[wave * 16 + kb * 4 + i]      = ssi[i];
            S[64 + wave * 16 + kb * 4 + i] = sst[i];
        }
    }
    __syncthreads();
    #pragma unroll
    for (int i = 0; i < 4; ++i) {
        int r = kb * 4 + i;
        float ti = S[r] + S[16 + r] + S[32 + r] + S[48 + r];     // fixed order
        float tt = S[64 + r] + S[80 + r] + S[96 + r] + S[112 + r];
        float rni = 1.0f / fmaxf(sqrtf(ti), 1e-12f);
        float rnt = 1.0f / fmaxf(sqrtf(tt), 1e-12f);
        egob_items[(size_t)(row0 + r) * 64 + 16 * wave + col] =
            pack_bf2(ai[i] * rni, at4[i] * rnt);
    }
}

// ---------------------------------------------------------------- scatter + user copy

__global__ __launch_bounds__(256) void scat_copy_kernel(
        const int* __restrict__ rows, const int* __restrict__ cols,
        const float* __restrict__ vals, int* __restrict__ cnt, int2* __restrict__ ell,
        const float* __restrict__ img_pref, const float* __restrict__ txt_pref,
        unsigned* __restrict__ egob) {
    int b = blockIdx.x;
    if (b < C_COPY) {
        int idx = b * 256 + threadIdx.x;
        int stride = C_COPY * 256;
        for (; idx < N_USERS * 16; idx += stride) {
            int row = idx >> 4, w4 = (idx & 15) << 2;
            float4 iv = *reinterpret_cast<const float4*>(&img_pref[(size_t)row * 64 + w4]);
            float4 tv = *reinterpret_cast<const float4*>(&txt_pref[(size_t)row * 64 + w4]);
            uint4 m;
            m.x = pack_bf2(iv.x, tv.x); m.y = pack_bf2(iv.y, tv.y);
            m.z = pack_bf2(iv.z, tv.z); m.w = pack_bf2(iv.w, tv.w);
            *reinterpret_cast<uint4*>(&egob[(size_t)row * 64 + w4]) = m;
        }
    } else {
        int i = (b - C_COPY) * 256 + threadIdx.x;
        int stride = C_SCAT * 256;
        for (; i < NNZ; i += stride) {
            int r = rows[i];
            int p = atomicAdd(&cnt[r], 1);
            if (p < ELL_CAP)
                ell[(size_t)r * ELL_CAP + p] = make_int2(cols[i], __float_as_int(vals[i]));
        }
    }
}

// ---------------------------------------------------------------- SpMM layer 1 + fused sort

__global__ __launch_bounds__(256) void spmm_sort_kernel(
        const int* __restrict__ cnt, int2* __restrict__ ell,
        const unsigned* __restrict__ xb, unsigned* __restrict__ outb) {
    __shared__ __align__(16) int2 srt[4][ELL_CAP];
    int wid = threadIdx.x >> 6, lane = threadIdx.x & 63;
    int row = blockIdx.x * 4 + wid;
    bool valid = row < N_TOTAL;
    int deg = 0;
    int2* base = nullptr;
    int2 e0 = make_int2(0x7FFFFFFF, 0), e1 = e0;
    if (valid) {
        deg = min(cnt[row], ELL_CAP);
        base = ell + (size_t)row * ELL_CAP;
        if (lane < deg)      e0 = base[lane];
        if (lane + 64 < deg) e1 = base[lane + 64];
    }
    #pragma unroll
    for (int k = 2; k <= 128; k <<= 1) {
        #pragma unroll
        for (int j = 64; j >= 1; j >>= 1) {
            if (j >= k) continue;
            if (j == 64) {
                if (e0.x > e1.x) { int2 tmp = e0; e0 = e1; e1 = tmp; }
            } else {
                int2 p0, p1;
                p0.x = __shfl_xor(e0.x, j, 64); p0.y = __shfl_xor(e0.y, j, 64);
                p1.x = __shfl_xor(e1.x, j, 64); p1.y = __shfl_xor(e1.y, j, 64);
                bool up0 = ((lane & k) == 0);
                bool up1 = (((lane + 64) & k) == 0);
                bool lo0 = ((lane & j) == 0);
                bool keepmin0 = (up0 == lo0);
                bool keepmin1 = (up1 == lo0);
                if (keepmin0 ? (e0.x > p0.x) : (e0.x < p0.x)) e0 = p0;
                if (keepmin1 ? (e1.x > p1.x) : (e1.x < p1.x)) e1 = p1;
            }
        }
    }
    if (valid) {
        if (lane < deg)      base[lane]      = e0;
        if (lane + 64 < deg) base[lane + 64] = e1;
    }
    srt[wid][lane] = e0;
    srt[wid][lane + 64] = e1;
    __syncthreads();
    if (!valid) return;
    unsigned sw = xb[(size_t)row * 64 + lane];
    float2 acc;
    acc.x = ALPHA_F * bf_lo(sw);
    acc.y = ALPHA_F * bf_hi(sw);
    const int2* s = srt[wid];
    int i = 0;
    for (; i + 8 <= deg; i += 8) {
        int4 p0 = *reinterpret_cast<const int4*>(s + i);
        int4 p1 = *reinterpret_cast<const int4*>(s + i + 2);
        int4 p2 = *reinterpret_cast<const int4*>(s + i + 4);
        int4 p3 = *reinterpret_cast<const int4*>(s + i + 6);
        unsigned g0 = xb[(size_t)p0.x * 64 + lane];
        unsigned g1 = xb[(size_t)p0.z * 64 + lane];
        unsigned g2 = xb[(size_t)p1.x * 64 + lane];
        unsigned g3 = xb[(size_t)p1.z * 64 + lane];
        unsigned g4 = xb[(size_t)p2.x * 64 + lane];
        unsigned g5 = xb[(size_t)p2.z * 64 + lane];
        unsigned g6 = xb[(size_t)p3.x * 64 + lane];
        unsigned g7 = xb[(size_t)p3.z * 64 + lane];
        float v0 = __int_as_float(p0.y), v1 = __int_as_float(p0.w);
        float v2 = __int_as_float(p1.y), v3 = __int_as_float(p1.w);
        float v4 = __int_as_float(p2.y), v5 = __int_as_float(p2.w);
        float v6 = __int_as_float(p3.y), v7 = __int_as_float(p3.w);
        acc.x = fmaf(v0, bf_lo(g0), acc.x); acc.y = fmaf(v0, bf_hi(g0), acc.y);
        acc.x = fmaf(v1, bf_lo(g1), acc.x); acc.y = fmaf(v1, bf_hi(g1), acc.y);
        acc.x = fmaf(v2, bf_lo(g2), acc.x); acc.y = fmaf(v2, bf_hi(g2), acc.y);
        acc.x = fmaf(v3, bf_lo(g3), acc.x); acc.y = fmaf(v3, bf_hi(g3), acc.y);
        acc.x = fmaf(v4, bf_lo(g4), acc.x); acc.y = fmaf(v4, bf_hi(g4), acc.y);
        acc.x = fmaf(v5, bf_lo(g5), acc.x); acc.y = fmaf(v5, bf_hi(g5), acc.y);
        acc.x = fmaf(v6, bf_lo(g6), acc.x); acc.y = fmaf(v6, bf_hi(g6), acc.y);
        acc.x = fmaf(v7, bf_lo(g7), acc.x); acc.y = fmaf(v7, bf_hi(g7), acc.y);
    }
    for (; i < deg; ++i) {
        int2 c = s[i];
        float v = __int_as_float(c.y);
        unsigned g = xb[(size_t)c.x * 64 + lane];
        acc.x = fmaf(v, bf_lo(g), acc.x);
        acc.y = fmaf(v, bf_hi(g), acc.y);
    }
    outb[(size_t)row * 64 + lane] = pack_bf2(acc.x, acc.y);
}

// ---------------------------------------------------------------- SpMM layers 2-3

__global__ __launch_bounds__(256) void spmm_kernel(
        const int* __restrict__ cnt, const int2* __restrict__ ell,
        const unsigned* __restrict__ xb,
        float* __restrict__ out32, unsigned* __restrict__ outb) {
    int row = blockIdx.x * 4 + (threadIdx.x >> 6);
    if (row >= N_TOTAL) return;
    int lane = threadIdx.x & 63;
    unsigned sw = xb[(size_t)row * 64 + lane];
    float2 acc;
    acc.x = ALPHA_F * bf_lo(sw);
    acc.y = ALPHA_F * bf_hi(sw);
    int deg = min(cnt[row], ELL_CAP);
    const int2* base = ell + (size_t)row * ELL_CAP;
    int i = 0;
    for (; i + 8 <= deg; i += 8) {
        int4 p0 = *reinterpret_cast<const int4*>(base + i);
        int4 p1 = *reinterpret_cast<const int4*>(base + i + 2);
        int4 p2 = *reinterpret_cast<const int4*>(base + i + 4);
        int4 p3 = *reinterpret_cast<const int4*>(base + i + 6);
        unsigned g0 = xb[(size_t)p0.x * 64 + lane];
        unsigned g1 = xb[(size_t)p0.z * 64 + lane];
        unsigned g2 = xb[(size_t)p1.x * 64 + lane];
        unsigned g3 = xb[(size_t)p1.z * 64 + lane];
        unsigned g4 = xb[(size_t)p2.x * 64 + lane];
        unsigned g5 = xb[(size_t)p2.z * 64 + lane];
        unsigned g6 = xb[(size_t)p3.x * 64 + lane];
        unsigned g7 = xb[(size_t)p3.z * 64 + lane];
        float v0 = __int_as_float(p0.y), v1 = __int_as_float(p0.w);
        float v2 = __int_as_float(p1.y), v3 = __int_as_float(p1.w);
        float v4 = __int_as_float(p2.y), v5 = __int_as_float(p2.w);
        float v6 = __int_as_float(p3.y), v7 = __int_as_float(p3.w);
        acc.x = fmaf(v0, bf_lo(g0), acc.x); acc.y = fmaf(v0, bf_hi(g0), acc.y);
        acc.x = fmaf(v1, bf_lo(g1), acc.x); acc.y = fmaf(v1, bf_hi(g1), acc.y);
        acc.x = fmaf(v2, bf_lo(g2), acc.x); acc.y = fmaf(v2, bf_hi(g2), acc.y);
        acc.x = fmaf(v3, bf_lo(g3), acc.x); acc.y = fmaf(v3, bf_hi(g3), acc.y);
        acc.x = fmaf(v4, bf_lo(g4), acc.x); acc.y = fmaf(v4, bf_hi(g4), acc.y);
        acc.x = fmaf(v5, bf_lo(g5), acc.x); acc.y = fmaf(v5, bf_hi(g5), acc.y);
        acc.x = fmaf(v6, bf_lo(g6), acc.x); acc.y = fmaf(v6, bf_hi(g6), acc.y);
        acc.x = fmaf(v7, bf_lo(g7), acc.x); acc.y = fmaf(v7, bf_hi(g7), acc.y);
    }
    for (; i < deg; ++i) {
        int2 c = base[i];
        float v = __int_as_float(c.y);
        unsigned g = xb[(size_t)c.x * 64 + lane];
        acc.x = fmaf(v, bf_lo(g), acc.x);
        acc.y = fmaf(v, bf_hi(g), acc.y);
    }
    if (out32) {
        out32[(size_t)row * 128 + lane] = acc.x;
        out32[(size_t)row * 128 + 64 + lane] = acc.y;
    }
    if (outb)
        outb[(size_t)row * 64 + lane] = pack_bf2(acc.x, acc.y);
}

// ---------------------------------------------------------------- launch

extern "C" void kernel_launch(void* const* d_in, const int* in_sizes, int n_in,
                              void* d_out, int out_size, void* d_ws, size_t ws_size,
                              hipStream_t stream) {
    const float* image_feats = (const float*)d_in[0];
    const float* text_feats  = (const float*)d_in[1];
    const float* image_pref  = (const float*)d_in[2];
    const float* text_pref   = (const float*)d_in[3];
    const float* W_img       = (const float*)d_in[4];
    const float* b_img       = (const float*)d_in[5];
    const float* W_txt       = (const float*)d_in[6];
    const float* b_txt       = (const float*)d_in[7];
    const float* adj_vals    = (const float*)d_in[8];
    const int*   adj_rows    = (const int*)d_in[9];
    const int*   adj_cols    = (const int*)d_in[10];

    float* out = (float*)d_out;                          // [150000*128]

    char* ws = (char*)d_ws;
    size_t off = 0;
    auto alloc = [&](size_t bytes) { char* p = ws + off; off += (bytes + 255) & ~size_t(255); return p; };
    int*      cnt   = (int*)     alloc(N_TOTAL * sizeof(int));
    int2*     ell   = (int2*)    alloc((size_t)N_TOTAL * ELL_CAP * sizeof(int2));
    unsigned* m0    = (unsigned*)alloc((size_t)N_TOTAL * 64 * sizeof(unsigned));
    unsigned* m1    = (unsigned*)alloc((size_t)N_TOTAL * 64 * sizeof(unsigned));
    char*     WtiT  = (char*)    alloc((size_t)NC_IMG * 16384);
    char*     WttT  = (char*)    alloc((size_t)3 * 16384);
    (void)ws_size; (void)out_size; (void)n_in; (void)in_sizes;

    // --- prep: zero cnt + tiled/swizzled bf16 B ---
    prep_kernel<<<512, 256, 0, stream>>>(W_img, W_txt, cnt, WtiT, WttT);

    // --- item GEMM (pure-LDS compute, counted-vmcnt prefetch) ---
    unsigned* m0_items = m0 + (size_t)N_USERS * 64;
    gemm_kernel<<<G_GEMM, 256, 0, stream>>>(
        image_feats, text_feats, WtiT, WttT, b_img, b_txt, m0_items);

    // --- scatter + user-pref copy ---
    scat_copy_kernel<<<C_COPY + C_SCAT, 256, 0, stream>>>(
        adj_rows, adj_cols, adj_vals, cnt, ell, image_pref, text_pref, m0);

    // --- layer 1 (+ canonical in-kernel sort), then layers 2-3 ---
    const int ROW_GRID = (N_TOTAL + 3) / 4;
    spmm_sort_kernel<<<ROW_GRID, 256, 0, stream>>>(cnt, ell, m0, m1);
    spmm_kernel<<<ROW_GRID, 256, 0, stream>>>(cnt, ell, m1, nullptr, m0);
    spmm_kernel<<<ROW_GRID, 256, 0, stream>>>(cnt, ell, m0, out, nullptr);
}

// Round 14
// 1014.769 us; speedup vs baseline: 1.0678x; 1.0099x over previous
//
#include <hip/hip_runtime.h>
#include <hip/hip_bf16.h>

#define N_USERS 100000
#define N_ITEMS 50000
#define N_TOTAL 150000
#define NNZ     4000000
#define ALPHA_F 0.8f
#define ELL_CAP 128

#define G_SCAT 1024
#define G_COPY 128
#define G_PRE  (G_SCAT + G_COPY)
#define G_GEMM 782            // ceil(50000/64)
#define NC_IMG 64             // img chunks of K=64
#define NC_ALL 70             // + 6 txt chunks of K=64

typedef __attribute__((ext_vector_type(8))) short bf16x8;
typedef __attribute__((ext_vector_type(4))) float f32x4;

static __device__ __forceinline__ short f2bf(float f) {
    unsigned u = __builtin_bit_cast(unsigned, f);
    unsigned r = (u + 0x7fff + ((u >> 16) & 1)) >> 16;   // RTNE
    return (short)r;
}
static __device__ __forceinline__ unsigned pack_bf2(float a, float b) {
    return (unsigned)(unsigned short)f2bf(a) | ((unsigned)(unsigned short)f2bf(b) << 16);
}
static __device__ __forceinline__ float bf_lo(unsigned u) { return __uint_as_float(u << 16); }
static __device__ __forceinline__ float bf_hi(unsigned u) { return __uint_as_float(u & 0xFFFF0000u); }

static __device__ __forceinline__ void gload_lds16(const void* src, void* dst) {
    __builtin_amdgcn_global_load_lds(
        (const __attribute__((address_space(1))) unsigned*)src,
        (__attribute__((address_space(3))) unsigned*)dst, 16, 0, 0);
}

// ---------------------------------------------------------------- prep
// zero cnt + tiled/swizzled bf16 B: per K=64 chunk c, tile[n][k'] 8KB,
// byte (k'*2) ^ ((n&7)<<4), n-stride 128B. img: 64 chunks; txt: 6.

__global__ __launch_bounds__(256) void prep_kernel(const float* __restrict__ Wimg,
                                                   const float* __restrict__ Wtxt,
                                                   int* __restrict__ cnt,
                                                   char* __restrict__ WtiT,
                                                   char* __restrict__ WttT) {
    const int T0 = N_TOTAL;
    const int T1 = T0 + 4096 * 64;
    const int T2 = T1 + 384 * 64;
    int i = blockIdx.x * 256 + threadIdx.x;
    int stride = gridDim.x * 256;
    for (; i < T2; i += stride) {
        if (i < T0) {
            cnt[i] = 0;
        } else if (i < T1) {
            int idx = i - T0; int k = idx >> 6, n = idx & 63;
            int c = k >> 6, kk = k & 63;
            *(short*)(WtiT + c * 8192 + n * 128 + ((kk * 2) ^ ((n & 7) << 4)))
                = f2bf(Wimg[(size_t)k * 64 + n]);
        } else {
            int idx = i - T1; int k = idx >> 6, n = idx & 63;
            int c = k >> 6, kk = k & 63;
            *(short*)(WttT + c * 8192 + n * 128 + ((kk * 2) ^ ((n & 7) << 4)))
                = f2bf(Wtxt[(size_t)k * 64 + n]);
        }
    }
}

// ---------------------------------------------------------------- mega kernel
// [0, G_SCAT):      ELL scatter
// [G_SCAT, G_PRE):  user pref -> bf16 mirror
// [G_PRE, ...):     item GEMM, 64 rows/block, K-chunk 64.
//   stage: A 16KB (4 gload/wave, pre-swizzled src) + B 8KB (2 gload/wave,
//   pre-tiled). comp = pure LDS+MFMA. counted vmcnt(6) across barriers.

__global__ __launch_bounds__(256, 3) void mega_kernel(
        const float* __restrict__ Aimg, const float* __restrict__ Atxt,
        const char* __restrict__ WtiT, const char* __restrict__ WttT,
        const float* __restrict__ bimg, const float* __restrict__ btxt,
        unsigned* __restrict__ egob,
        const int* __restrict__ rows, const int* __restrict__ cols,
        const float* __restrict__ vals, int* __restrict__ cnt, int2* __restrict__ ell,
        const float* __restrict__ img_pref, const float* __restrict__ txt_pref) {
    __shared__ __align__(16) char abuf[2][16384];
    __shared__ __align__(16) char bbuf[2][8192];
    int b = blockIdx.x;
    int t = threadIdx.x;
    int wave = t >> 6, lane = t & 63;

    if (b < G_SCAT) {
        int i = b * 256 + t;
        int stride = G_SCAT * 256;
        for (; i < NNZ; i += stride) {
            int r = rows[i];
            int p = atomicAdd(&cnt[r], 1);
            if (p < ELL_CAP)
                ell[(size_t)r * ELL_CAP + p] = make_int2(cols[i], __float_as_int(vals[i]));
        }
        return;
    }
    if (b < G_PRE) {
        int idx = (b - G_SCAT) * 256 + t;
        int stride = G_COPY * 256;
        for (; idx < N_USERS * 16; idx += stride) {
            int row = idx >> 4, w4 = (idx & 15) << 2;
            float4 iv = *reinterpret_cast<const float4*>(&img_pref[(size_t)row * 64 + w4]);
            float4 tv = *reinterpret_cast<const float4*>(&txt_pref[(size_t)row * 64 + w4]);
            uint4 m;
            m.x = pack_bf2(iv.x, tv.x); m.y = pack_bf2(iv.y, tv.y);
            m.z = pack_bf2(iv.z, tv.z); m.w = pack_bf2(iv.w, tv.w);
            *reinterpret_cast<uint4*>(&egob[(size_t)row * 64 + w4]) = m;
        }
        return;
    }

    // ---------------- GEMM ----------------
    const int blk = b - G_PRE;
    const int row0 = blk * 64;
    const int col = lane & 15, kb = lane >> 4;
    const int gmax = N_ITEMS - 1;

    auto stage = [&](int ci, int bi) {
        const float* A; size_t rowbytes; const char* BT; int cc;
        if (ci < NC_IMG) { A = Aimg; rowbytes = 16384; BT = WtiT; cc = ci; }
        else             { A = Atxt; rowbytes = 1536;  BT = WttT; cc = ci - NC_IMG; }
        // A: 4 calls/wave; call g covers rows 4g..4g+3 (256B each)
        #pragma unroll
        for (int q = 0; q < 4; ++q) {
            int g = q * 4 + wave;
            int r = g * 4 + (lane >> 4);
            int gr = row0 + r; gr = gr > gmax ? gmax : gr;
            int so = ((lane & 15) * 16) ^ ((r & 7) << 4);
            const char* src = (const char*)A + (size_t)gr * rowbytes + cc * 256 + so;
            char* dst = abuf[bi] + g * 1024 + lane * 16;
            gload_lds16(src, dst);
        }
        // B: 2 calls/wave, fully linear (tiled layout already swizzled)
        #pragma unroll
        for (int q = 0; q < 2; ++q) {
            int off = (q * 4 + wave) * 1024 + lane * 16;
            gload_lds16(BT + (size_t)cc * 8192 + off, bbuf[bi] + off);
        }
    };

    // comp: 2 k-steps x 4 n-tiles; A row = 16*wave+col (256B/row, swizzled)
    auto comp = [&](int bi, f32x4& c0, f32x4& c1, f32x4& c2, f32x4& c3) {
        const int arow = 16 * wave + col;
        const int aswz = (arow & 7) << 4;
        const char* ab = abuf[bi] + arow * 256;
        const char* bb = bbuf[bi];
        const int bswz = (col & 7) << 4;
        #pragma unroll
        for (int ks = 0; ks < 2; ++ks) {
            int la = ks * 128 + kb * 32;
            float4 a0 = *(const float4*)(ab + (la ^ aswz));
            float4 a1 = *(const float4*)(ab + ((la + 16) ^ aswz));
            bf16x8 af;
            af[0]=f2bf(a0.x); af[1]=f2bf(a0.y); af[2]=f2bf(a0.z); af[3]=f2bf(a0.w);
            af[4]=f2bf(a1.x); af[5]=f2bf(a1.y); af[6]=f2bf(a1.z); af[7]=f2bf(a1.w);
            int kByte = (ks * 64 + kb * 16) ^ bswz;
            bf16x8 b0 = *(const bf16x8*)(bb + (col +  0) * 128 + kByte);
            bf16x8 b1 = *(const bf16x8*)(bb + (col + 16) * 128 + kByte);
            bf16x8 b2 = *(const bf16x8*)(bb + (col + 32) * 128 + kByte);
            bf16x8 b3 = *(const bf16x8*)(bb + (col + 48) * 128 + kByte);
            c0 = __builtin_amdgcn_mfma_f32_16x16x32_bf16(af, b0, c0, 0, 0, 0);
            c1 = __builtin_amdgcn_mfma_f32_16x16x32_bf16(af, b1, c1, 0, 0, 0);
            c2 = __builtin_amdgcn_mfma_f32_16x16x32_bf16(af, b2, c2, 0, 0, 0);
            c3 = __builtin_amdgcn_mfma_f32_16x16x32_bf16(af, b3, c3, 0, 0, 0);
        }
    };

    f32x4 z = {0.f,0.f,0.f,0.f};
    f32x4 ai0 = z, ai1 = z, ai2 = z, ai3 = z;
    f32x4 at0 = z, at1 = z, at2 = z, at3 = z;

    stage(0, 0);
    for (int ci = 0; ci < NC_ALL; ++ci) {
        int bi = ci & 1;
        if (ci + 1 < NC_ALL) {
            stage(ci + 1, bi ^ 1);
            asm volatile("s_waitcnt vmcnt(6)" ::: "memory");   // my stage(ci) done; prefetch in flight
        } else {
            asm volatile("s_waitcnt vmcnt(0)" ::: "memory");
        }
        __builtin_amdgcn_s_barrier();
        __builtin_amdgcn_sched_barrier(0);
        if (ci < NC_IMG) comp(bi, ai0, ai1, ai2, ai3);
        else             comp(bi, at0, at1, at2, at3);
        __builtin_amdgcn_sched_barrier(0);
        __builtin_amdgcn_s_barrier();
    }

    // ---------------- bias + wave-local L2 norm + mirror store ----------------
    float bi0 = bimg[ 0 + col], bi1 = bimg[16 + col], bi2 = bimg[32 + col], bi3 = bimg[48 + col];
    float bt0 = btxt[ 0 + col], bt1 = btxt[16 + col], bt2 = btxt[32 + col], bt3 = btxt[48 + col];
    #pragma unroll
    for (int i = 0; i < 4; ++i) {
        ai0[i] += bi0; ai1[i] += bi1; ai2[i] += bi2; ai3[i] += bi3;
        at0[i] += bt0; at1[i] += bt1; at2[i] += bt2; at3[i] += bt3;
    }
    unsigned* egob_items = egob + (size_t)N_USERS * 64;
    #pragma unroll
    for (int i = 0; i < 4; ++i) {
        float ssi = ai0[i]*ai0[i] + ai1[i]*ai1[i] + ai2[i]*ai2[i] + ai3[i]*ai3[i];
        float sst = at0[i]*at0[i] + at1[i]*at1[i] + at2[i]*at2[i] + at3[i]*at3[i];
        #pragma unroll
        for (int off = 1; off < 16; off <<= 1) {
            ssi += __shfl_xor(ssi, off, 64);
            sst += __shfl_xor(sst, off, 64);
        }
        float rni = 1.0f / fmaxf(sqrtf(ssi), 1e-12f);
        float rnt = 1.0f / fmaxf(sqrtf(sst), 1e-12f);
        int r = row0 + 16 * wave + kb * 4 + i;
        if (r < N_ITEMS) {
            unsigned* ob = egob_items + (size_t)r * 64 + col;
            ob[ 0] = pack_bf2(ai0[i]*rni, at0[i]*rnt);
            ob[16] = pack_bf2(ai1[i]*rni, at1[i]*rnt);
            ob[32] = pack_bf2(ai2[i]*rni, at2[i]*rnt);
            ob[48] = pack_bf2(ai3[i]*rni, at3[i]*rnt);
        }
    }
}

// ---------------------------------------------------------------- SpMM layer 1 + fused sort

__global__ __launch_bounds__(256) void spmm_sort_kernel(
        const int* __restrict__ cnt, int2* __restrict__ ell,
        const unsigned* __restrict__ xb, unsigned* __restrict__ outb) {
    __shared__ __align__(16) int2 srt[4][ELL_CAP];
    int wid = threadIdx.x >> 6, lane = threadIdx.x & 63;
    int row = blockIdx.x * 4 + wid;
    bool valid = row < N_TOTAL;
    int deg = 0;
    int2* base = nullptr;
    int2 e0 = make_int2(0x7FFFFFFF, 0), e1 = e0;
    if (valid) {
        deg = min(cnt[row], ELL_CAP);
        base = ell + (size_t)row * ELL_CAP;
        if (lane < deg)      e0 = base[lane];
        if (lane + 64 < deg) e1 = base[lane + 64];
    }
    #pragma unroll
    for (int k = 2; k <= 128; k <<= 1) {
        #pragma unroll
        for (int j = 64; j >= 1; j >>= 1) {
            if (j >= k) continue;
            if (j == 64) {
                if (e0.x > e1.x) { int2 tmp = e0; e0 = e1; e1 = tmp; }
            } else {
                int2 p0, p1;
                p0.x = __shfl_xor(e0.x, j, 64); p0.y = __shfl_xor(e0.y, j, 64);
                p1.x = __shfl_xor(e1.x, j, 64); p1.y = __shfl_xor(e1.y, j, 64);
                bool up0 = ((lane & k) == 0);
                bool up1 = (((lane + 64) & k) == 0);
                bool lo0 = ((lane & j) == 0);
                bool keepmin0 = (up0 == lo0);
                bool keepmin1 = (up1 == lo0);
                if (keepmin0 ? (e0.x > p0.x) : (e0.x < p0.x)) e0 = p0;
                if (keepmin1 ? (e1.x > p1.x) : (e1.x < p1.x)) e1 = p1;
            }
        }
    }
    if (valid) {
        if (lane < deg)      base[lane]      = e0;
        if (lane + 64 < deg) base[lane + 64] = e1;
    }
    srt[wid][lane] = e0;
    srt[wid][lane + 64] = e1;
    __syncthreads();
    if (!valid) return;
    unsigned sw = xb[(size_t)row * 64 + lane];
    float2 acc;
    acc.x = ALPHA_F * bf_lo(sw);
    acc.y = ALPHA_F * bf_hi(sw);
    const int2* s = srt[wid];
    int i = 0;
    for (; i + 8 <= deg; i += 8) {
        int4 p0 = *reinterpret_cast<const int4*>(s + i);
        int4 p1 = *reinterpret_cast<const int4*>(s + i + 2);
        int4 p2 = *reinterpret_cast<const int4*>(s + i + 4);
        int4 p3 = *reinterpret_cast<const int4*>(s + i + 6);
        unsigned g0 = xb[(size_t)p0.x * 64 + lane];
        unsigned g1 = xb[(size_t)p0.z * 64 + lane];
        unsigned g2 = xb[(size_t)p1.x * 64 + lane];
        unsigned g3 = xb[(size_t)p1.z * 64 + lane];
        unsigned g4 = xb[(size_t)p2.x * 64 + lane];
        unsigned g5 = xb[(size_t)p2.z * 64 + lane];
        unsigned g6 = xb[(size_t)p3.x * 64 + lane];
        unsigned g7 = xb[(size_t)p3.z * 64 + lane];
        float v0 = __int_as_float(p0.y), v1 = __int_as_float(p0.w);
        float v2 = __int_as_float(p1.y), v3 = __int_as_float(p1.w);
        float v4 = __int_as_float(p2.y), v5 = __int_as_float(p2.w);
        float v6 = __int_as_float(p3.y), v7 = __int_as_float(p3.w);
        acc.x = fmaf(v0, bf_lo(g0), acc.x); acc.y = fmaf(v0, bf_hi(g0), acc.y);
        acc.x = fmaf(v1, bf_lo(g1), acc.x); acc.y = fmaf(v1, bf_hi(g1), acc.y);
        acc.x = fmaf(v2, bf_lo(g2), acc.x); acc.y = fmaf(v2, bf_hi(g2), acc.y);
        acc.x = fmaf(v3, bf_lo(g3), acc.x); acc.y = fmaf(v3, bf_hi(g3), acc.y);
        acc.x = fmaf(v4, bf_lo(g4), acc.x); acc.y = fmaf(v4, bf_hi(g4), acc.y);
        acc.x = fmaf(v5, bf_lo(g5), acc.x); acc.y = fmaf(v5, bf_hi(g5), acc.y);
        acc.x = fmaf(v6, bf_lo(g6), acc.x); acc.y = fmaf(v6, bf_hi(g6), acc.y);
        acc.x = fmaf(v7, bf_lo(g7), acc.x); acc.y = fmaf(v7, bf_hi(g7), acc.y);
    }
    for (; i < deg; ++i) {
        int2 c = s[i];
        float v = __int_as_float(c.y);
        unsigned g = xb[(size_t)c.x * 64 + lane];
        acc.x = fmaf(v, bf_lo(g), acc.x);
        acc.y = fmaf(v, bf_hi(g), acc.y);
    }
    outb[(size_t)row * 64 + lane] = pack_bf2(acc.x, acc.y);
}

// ---------------------------------------------------------------- SpMM layers 2-3

__global__ __launch_bounds__(256) void spmm_kernel(
        const int* __restrict__ cnt, const int2* __restrict__ ell,
        const unsigned* __restrict__ xb,
        float* __restrict__ out32, unsigned* __restrict__ outb) {
    int row = blockIdx.x * 4 + (threadIdx.x >> 6);
    if (row >= N_TOTAL) return;
    int lane = threadIdx.x & 63;
    unsigned sw = xb[(size_t)row * 64 + lane];
    float2 acc;
    acc.x = ALPHA_F * bf_lo(sw);
    acc.y = ALPHA_F * bf_hi(sw);
    int deg = min(cnt[row], ELL_CAP);
    const int2* base = ell + (size_t)row * ELL_CAP;
    int i = 0;
    for (; i + 8 <= deg; i += 8) {
        int4 p0 = *reinterpret_cast<const int4*>(base + i);
        int4 p1 = *reinterpret_cast<const int4*>(base + i + 2);
        int4 p2 = *reinterpret_cast<const int4*>(base + i + 4);
        int4 p3 = *reinterpret_cast<const int4*>(base + i + 6);
        unsigned g0 = xb[(size_t)p0.x * 64 + lane];
        unsigned g1 = xb[(size_t)p0.z * 64 + lane];
        unsigned g2 = xb[(size_t)p1.x * 64 + lane];
        unsigned g3 = xb[(size_t)p1.z * 64 + lane];
        unsigned g4 = xb[(size_t)p2.x * 64 + lane];
        unsigned g5 = xb[(size_t)p2.z * 64 + lane];
        unsigned g6 = xb[(size_t)p3.x * 64 + lane];
        unsigned g7 = xb[(size_t)p3.z * 64 + lane];
        float v0 = __int_as_float(p0.y), v1 = __int_as_float(p0.w);
        float v2 = __int_as_float(p1.y), v3 = __int_as_float(p1.w);
        float v4 = __int_as_float(p2.y), v5 = __int_as_float(p2.w);
        float v6 = __int_as_float(p3.y), v7 = __int_as_float(p3.w);
        acc.x = fmaf(v0, bf_lo(g0), acc.x); acc.y = fmaf(v0, bf_hi(g0), acc.y);
        acc.x = fmaf(v1, bf_lo(g1), acc.x); acc.y = fmaf(v1, bf_hi(g1), acc.y);
        acc.x = fmaf(v2, bf_lo(g2), acc.x); acc.y = fmaf(v2, bf_hi(g2), acc.y);
        acc.x = fmaf(v3, bf_lo(g3), acc.x); acc.y = fmaf(v3, bf_hi(g3), acc.y);
        acc.x = fmaf(v4, bf_lo(g4), acc.x); acc.y = fmaf(v4, bf_hi(g4), acc.y);
        acc.x = fmaf(v5, bf_lo(g5), acc.x); acc.y = fmaf(v5, bf_hi(g5), acc.y);
        acc.x = fmaf(v6, bf_lo(g6), acc.x); acc.y = fmaf(v6, bf_hi(g6), acc.y);
        acc.x = fmaf(v7, bf_lo(g7), acc.x); acc.y = fmaf(v7, bf_hi(g7), acc.y);
    }
    for (; i < deg; ++i) {
        int2 c = base[i];
        float v = __int_as_float(c.y);
        unsigned g = xb[(size_t)c.x * 64 + lane];
        acc.x = fmaf(v, bf_lo(g), acc.x);
        acc.y = fmaf(v, bf_hi(g), acc.y);
    }
    if (out32) {
        out32[(size_t)row * 128 + lane] = acc.x;
        out32[(size_t)row * 128 + 64 + lane] = acc.y;
    }
    if (outb)
        outb[(size_t)row * 64 + lane] = pack_bf2(acc.x, acc.y);
}

// ---------------------------------------------------------------- launch

extern "C" void kernel_launch(void* const* d_in, const int* in_sizes, int n_in,
                              void* d_out, int out_size, void* d_ws, size_t ws_size,
                              hipStream_t stream) {
    const float* image_feats = (const float*)d_in[0];
    const float* text_feats  = (const float*)d_in[1];
    const float* image_pref  = (const float*)d_in[2];
    const float* text_pref   = (const float*)d_in[3];
    const float* W_img       = (const float*)d_in[4];
    const float* b_img       = (const float*)d_in[5];
    const float* W_txt       = (const float*)d_in[6];
    const float* b_txt       = (const float*)d_in[7];
    const float* adj_vals    = (const float*)d_in[8];
    const int*   adj_rows    = (const int*)d_in[9];
    const int*   adj_cols    = (const int*)d_in[10];

    float* out = (float*)d_out;                          // [150000*128]

    char* ws = (char*)d_ws;
    size_t off = 0;
    auto alloc = [&](size_t bytes) { char* p = ws + off; off += (bytes + 255) & ~size_t(255); return p; };
    int*      cnt   = (int*)     alloc(N_TOTAL * sizeof(int));
    int2*     ell   = (int2*)    alloc((size_t)N_TOTAL * ELL_CAP * sizeof(int2));
    unsigned* m0    = (unsigned*)alloc((size_t)N_TOTAL * 64 * sizeof(unsigned));
    unsigned* m1    = (unsigned*)alloc((size_t)N_TOTAL * 64 * sizeof(unsigned));
    char*     WtiT  = (char*)    alloc((size_t)NC_IMG * 8192);
    char*     WttT  = (char*)    alloc((size_t)6 * 8192);
    (void)ws_size; (void)out_size; (void)n_in; (void)in_sizes;

    // --- prep: zero cnt + tiled/swizzled bf16 B ---
    prep_kernel<<<512, 256, 0, stream>>>(W_img, W_txt, cnt, WtiT, WttT);

    // --- mega: scatter || copy || GEMM (pure-LDS compute, counted vmcnt) ---
    mega_kernel<<<G_PRE + G_GEMM, 256, 0, stream>>>(
        image_feats, text_feats, WtiT, WttT, b_img, b_txt, m0,
        adj_rows, adj_cols, adj_vals, cnt, ell, image_pref, text_pref);

    // --- layer 1 (+ canonical in-kernel sort), then layers 2-3 ---
    const int ROW_GRID = (N_TOTAL + 3) / 4;
    spmm_sort_kernel<<<ROW_GRID, 256, 0, stream>>>(cnt, ell, m0, m1);
    spmm_kernel<<<ROW_GRID, 256, 0, stream>>>(cnt, ell, m1, nullptr, m0);
    spmm_kernel<<<ROW_GRID, 256, 0, stream>>>(cnt, ell, m0, out, nullptr);
}

// Round 15
// 966.781 us; speedup vs baseline: 1.1208x; 1.0496x over previous
//
#include <hip/hip_runtime.h>
#include <hip/hip_bf16.h>

#define N_USERS 100000
#define N_ITEMS 50000
#define N_TOTAL 150000
#define NNZ     4000000
#define ALPHA_F 0.8f
#define ELL_CAP 128

#define G_SCAT 1024
#define G_COPY 128
#define G_PRE  (G_SCAT + G_COPY)
#define G_GEMM 3125           // N_ITEMS / 16 exactly
#define NC_IMG 64             // img chunks of K=64
#define NC_ALL 70             // + 6 txt chunks of K=64

typedef __attribute__((ext_vector_type(8))) short bf16x8;
typedef __attribute__((ext_vector_type(4))) float f32x4;

static __device__ __forceinline__ short f2bf(float f) {
    unsigned u = __builtin_bit_cast(unsigned, f);
    unsigned r = (u + 0x7fff + ((u >> 16) & 1)) >> 16;   // RTNE
    return (short)r;
}
static __device__ __forceinline__ unsigned pack_bf2(float a, float b) {
    return (unsigned)(unsigned short)f2bf(a) | ((unsigned)(unsigned short)f2bf(b) << 16);
}
static __device__ __forceinline__ float bf_lo(unsigned u) { return __uint_as_float(u << 16); }
static __device__ __forceinline__ float bf_hi(unsigned u) { return __uint_as_float(u & 0xFFFF0000u); }

static __device__ __forceinline__ void gload_lds16(const void* src, void* dst) {
    __builtin_amdgcn_global_load_lds(
        (const __attribute__((address_space(1))) unsigned*)src,
        (__attribute__((address_space(3))) unsigned*)dst, 16, 0, 0);
}

// ---------------------------------------------------------------- prep
// zero cnt + tiled/swizzled bf16 B: per K=64 chunk c, tile[n][k'] 8KB,
// byte (k'*2) ^ ((n&7)<<4), n-stride 128B. img: 64 chunks; txt: 6.

__global__ __launch_bounds__(256) void prep_kernel(const float* __restrict__ Wimg,
                                                   const float* __restrict__ Wtxt,
                                                   int* __restrict__ cnt,
                                                   char* __restrict__ WtiT,
                                                   char* __restrict__ WttT) {
    const int T0 = N_TOTAL;
    const int T1 = T0 + 4096 * 64;
    const int T2 = T1 + 384 * 64;
    int i = blockIdx.x * 256 + threadIdx.x;
    int stride = gridDim.x * 256;
    for (; i < T2; i += stride) {
        if (i < T0) {
            cnt[i] = 0;
        } else if (i < T1) {
            int idx = i - T0; int k = idx >> 6, n = idx & 63;
            int c = k >> 6, kk = k & 63;
            *(short*)(WtiT + c * 8192 + n * 128 + ((kk * 2) ^ ((n & 7) << 4)))
                = f2bf(Wimg[(size_t)k * 64 + n]);
        } else {
            int idx = i - T1; int k = idx >> 6, n = idx & 63;
            int c = k >> 6, kk = k & 63;
            *(short*)(WttT + c * 8192 + n * 128 + ((kk * 2) ^ ((n & 7) << 4)))
                = f2bf(Wtxt[(size_t)k * 64 + n]);
        }
    }
}

// ---------------------------------------------------------------- mega kernel
// [0, G_SCAT):      ELL scatter (dispatched first -> co-resident with GEMM)
// [G_SCAT, G_PRE):  user pref -> bf16 mirror
// [G_PRE, ...):     item GEMM, 16 rows/block, K-chunk 64; LDS 24KB dbuf ->
//   6 blocks/CU. stage = 3 gload_lds/wave (A 1 + B 2); comp = pure LDS+MFMA
//   (no vmem) so counted vmcnt(3) keeps the prefetch in flight across barriers.

__global__ __launch_bounds__(256, 6) void mega_kernel(
        const float* __restrict__ Aimg, const float* __restrict__ Atxt,
        const char* __restrict__ WtiT, const char* __restrict__ WttT,
        const float* __restrict__ bimg, const float* __restrict__ btxt,
        unsigned* __restrict__ egob,
        const int* __restrict__ rows, const int* __restrict__ cols,
        const float* __restrict__ vals, int* __restrict__ cnt, int2* __restrict__ ell,
        const float* __restrict__ img_pref, const float* __restrict__ txt_pref) {
    __shared__ __align__(16) char abuf[2][4096];
    __shared__ __align__(16) char bbuf[2][8192];
    int b = blockIdx.x;
    int t = threadIdx.x;
    int wave = t >> 6, lane = t & 63;

    if (b < G_SCAT) {
        int i = b * 256 + t;
        int stride = G_SCAT * 256;
        for (; i < NNZ; i += stride) {
            int r = rows[i];
            int p = atomicAdd(&cnt[r], 1);
            if (p < ELL_CAP)
                ell[(size_t)r * ELL_CAP + p] = make_int2(cols[i], __float_as_int(vals[i]));
        }
        return;
    }
    if (b < G_PRE) {
        int idx = (b - G_SCAT) * 256 + t;
        int stride = G_COPY * 256;
        for (; idx < N_USERS * 16; idx += stride) {
            int row = idx >> 4, w4 = (idx & 15) << 2;
            float4 iv = *reinterpret_cast<const float4*>(&img_pref[(size_t)row * 64 + w4]);
            float4 tv = *reinterpret_cast<const float4*>(&txt_pref[(size_t)row * 64 + w4]);
            uint4 m;
            m.x = pack_bf2(iv.x, tv.x); m.y = pack_bf2(iv.y, tv.y);
            m.z = pack_bf2(iv.z, tv.z); m.w = pack_bf2(iv.w, tv.w);
            *reinterpret_cast<uint4*>(&egob[(size_t)row * 64 + w4]) = m;
        }
        return;
    }

    // ---------------- GEMM ----------------
    const int blk = b - G_PRE;
    const int row0 = blk * 16;
    const int col = lane & 15, kb = lane >> 4;

    auto stage = [&](int ci, int bi) {
        const float* A; size_t rowbytes; const char* BT; int cc;
        if (ci < NC_IMG) { A = Aimg; rowbytes = 16384; BT = WtiT; cc = ci; }
        else             { A = Atxt; rowbytes = 1536;  BT = WttT; cc = ci - NC_IMG; }
        // A: 1 call/wave; wave covers rows wave*4..wave*4+3 (256B per row chunk)
        {
            int r = wave * 4 + (lane >> 4);
            int so = ((lane & 15) * 16) ^ ((r & 7) << 4);
            const char* src = (const char*)A + (size_t)(row0 + r) * rowbytes + cc * 256 + so;
            char* dst = abuf[bi] + wave * 1024 + lane * 16;
            gload_lds16(src, dst);
        }
        // B: 2 calls/wave, fully linear (tiled layout already swizzled)
        #pragma unroll
        for (int q = 0; q < 2; ++q) {
            int off = (q * 4 + wave) * 1024 + lane * 16;
            gload_lds16(BT + (size_t)cc * 8192 + off, bbuf[bi] + off);
        }
    };

    // comp: 2 k-steps; A-frag row=col (256B/row, swizzled), B-frag n=16*wave+col
    auto comp = [&](int bi, f32x4& acc) {
        const int r = col;
        const int aswz = (r & 7) << 4;
        const char* ab = abuf[bi] + r * 256;
        const int n = 16 * wave + col;
        const char* bb = bbuf[bi] + n * 128;
        const int bswz = (n & 7) << 4;
        #pragma unroll
        for (int ks = 0; ks < 2; ++ks) {
            int la = ks * 128 + kb * 32;
            float4 a0 = *(const float4*)(ab + (la ^ aswz));
            float4 a1 = *(const float4*)(ab + ((la + 16) ^ aswz));
            bf16x8 af;
            af[0]=f2bf(a0.x); af[1]=f2bf(a0.y); af[2]=f2bf(a0.z); af[3]=f2bf(a0.w);
            af[4]=f2bf(a1.x); af[5]=f2bf(a1.y); af[6]=f2bf(a1.z); af[7]=f2bf(a1.w);
            bf16x8 bf = *(const bf16x8*)(bb + ((ks * 64 + kb * 16) ^ bswz));
            acc = __builtin_amdgcn_mfma_f32_16x16x32_bf16(af, bf, acc, 0, 0, 0);
        }
    };

    f32x4 ai = {0.f,0.f,0.f,0.f}, at4 = {0.f,0.f,0.f,0.f};

    stage(0, 0);
    for (int ci = 0; ci < NC_ALL; ++ci) {
        int bi = ci & 1;
        if (ci + 1 < NC_ALL) {
            stage(ci + 1, bi ^ 1);
            asm volatile("s_waitcnt vmcnt(3)" ::: "memory");   // stage(ci) done; next in flight
        } else {
            asm volatile("s_waitcnt vmcnt(0)" ::: "memory");
        }
        __builtin_amdgcn_s_barrier();
        __builtin_amdgcn_sched_barrier(0);
        if (ci < NC_IMG) comp(bi, ai);
        else             comp(bi, at4);
        __builtin_amdgcn_sched_barrier(0);
        __builtin_amdgcn_s_barrier();
    }

    // ---------------- bias + cross-wave L2 norm + mirror store ----------------
    float bv_i = bimg[16 * wave + col];
    float bv_t = btxt[16 * wave + col];
    float ssi[4], sst[4];
    #pragma unroll
    for (int i = 0; i < 4; ++i) {
        ai[i] += bv_i; at4[i] += bv_t;
        ssi[i] = ai[i] * ai[i];
        sst[i] = at4[i] * at4[i];
    }
    #pragma unroll
    for (int off = 1; off < 16; off <<= 1) {
        #pragma unroll
        for (int i = 0; i < 4; ++i) {
            ssi[i] += __shfl_xor(ssi[i], off, 64);
            sst[i] += __shfl_xor(sst[i], off, 64);
        }
    }
    float* S = (float*)abuf;           // [2][4 waves][16 rows] = 512B
    __syncthreads();                   // compute reads done; safe to reuse LDS
    if (col == 0) {
        #pragma unroll
        for (int i = 0; i < 4; ++i) {
            S[wave * 16 + kb * 4 + i]      = ssi[i];
            S[64 + wave * 16 + kb * 4 + i] = sst[i];
        }
    }
    __syncthreads();
    unsigned* egob_items = egob + (size_t)N_USERS * 64;
    #pragma unroll
    for (int i = 0; i < 4; ++i) {
        int r = kb * 4 + i;
        float ti = S[r] + S[16 + r] + S[32 + r] + S[48 + r];     // fixed order
        float tt = S[64 + r] + S[80 + r] + S[96 + r] + S[112 + r];
        float rni = 1.0f / fmaxf(sqrtf(ti), 1e-12f);
        float rnt = 1.0f / fmaxf(sqrtf(tt), 1e-12f);
        egob_items[(size_t)(row0 + r) * 64 + 16 * wave + col] =
            pack_bf2(ai[i] * rni, at4[i] * rnt);
    }
}

// ---------------------------------------------------------------- SpMM layer 1 + fused sort

__global__ __launch_bounds__(256) void spmm_sort_kernel(
        const int* __restrict__ cnt, int2* __restrict__ ell,
        const unsigned* __restrict__ xb, unsigned* __restrict__ outb) {
    __shared__ __align__(16) int2 srt[4][ELL_CAP];
    int wid = threadIdx.x >> 6, lane = threadIdx.x & 63;
    int row = blockIdx.x * 4 + wid;
    bool valid = row < N_TOTAL;
    int deg = 0;
    int2* base = nullptr;
    int2 e0 = make_int2(0x7FFFFFFF, 0), e1 = e0;
    if (valid) {
        deg = min(cnt[row], ELL_CAP);
        base = ell + (size_t)row * ELL_CAP;
        if (lane < deg)      e0 = base[lane];
        if (lane + 64 < deg) e1 = base[lane + 64];
    }
    #pragma unroll
    for (int k = 2; k <= 128; k <<= 1) {
        #pragma unroll
        for (int j = 64; j >= 1; j >>= 1) {
            if (j >= k) continue;
            if (j == 64) {
                if (e0.x > e1.x) { int2 tmp = e0; e0 = e1; e1 = tmp; }
            } else {
                int2 p0, p1;
                p0.x = __shfl_xor(e0.x, j, 64); p0.y = __shfl_xor(e0.y, j, 64);
                p1.x = __shfl_xor(e1.x, j, 64); p1.y = __shfl_xor(e1.y, j, 64);
                bool up0 = ((lane & k) == 0);
                bool up1 = (((lane + 64) & k) == 0);
                bool lo0 = ((lane & j) == 0);
                bool keepmin0 = (up0 == lo0);
                bool keepmin1 = (up1 == lo0);
                if (keepmin0 ? (e0.x > p0.x) : (e0.x < p0.x)) e0 = p0;
                if (keepmin1 ? (e1.x > p1.x) : (e1.x < p1.x)) e1 = p1;
            }
        }
    }
    if (valid) {
        if (lane < deg)      base[lane]      = e0;
        if (lane + 64 < deg) base[lane + 64] = e1;
    }
    srt[wid][lane] = e0;
    srt[wid][lane + 64] = e1;
    __syncthreads();
    if (!valid) return;
    unsigned sw = xb[(size_t)row * 64 + lane];
    float2 acc;
    acc.x = ALPHA_F * bf_lo(sw);
    acc.y = ALPHA_F * bf_hi(sw);
    const int2* s = srt[wid];
    int i = 0;
    for (; i + 8 <= deg; i += 8) {
        int4 p0 = *reinterpret_cast<const int4*>(s + i);
        int4 p1 = *reinterpret_cast<const int4*>(s + i + 2);
        int4 p2 = *reinterpret_cast<const int4*>(s + i + 4);
        int4 p3 = *reinterpret_cast<const int4*>(s + i + 6);
        unsigned g0 = xb[(size_t)p0.x * 64 + lane];
        unsigned g1 = xb[(size_t)p0.z * 64 + lane];
        unsigned g2 = xb[(size_t)p1.x * 64 + lane];
        unsigned g3 = xb[(size_t)p1.z * 64 + lane];
        unsigned g4 = xb[(size_t)p2.x * 64 + lane];
        unsigned g5 = xb[(size_t)p2.z * 64 + lane];
        unsigned g6 = xb[(size_t)p3.x * 64 + lane];
        unsigned g7 = xb[(size_t)p3.z * 64 + lane];
        float v0 = __int_as_float(p0.y), v1 = __int_as_float(p0.w);
        float v2 = __int_as_float(p1.y), v3 = __int_as_float(p1.w);
        float v4 = __int_as_float(p2.y), v5 = __int_as_float(p2.w);
        float v6 = __int_as_float(p3.y), v7 = __int_as_float(p3.w);
        acc.x = fmaf(v0, bf_lo(g0), acc.x); acc.y = fmaf(v0, bf_hi(g0), acc.y);
        acc.x = fmaf(v1, bf_lo(g1), acc.x); acc.y = fmaf(v1, bf_hi(g1), acc.y);
        acc.x = fmaf(v2, bf_lo(g2), acc.x); acc.y = fmaf(v2, bf_hi(g2), acc.y);
        acc.x = fmaf(v3, bf_lo(g3), acc.x); acc.y = fmaf(v3, bf_hi(g3), acc.y);
        acc.x = fmaf(v4, bf_lo(g4), acc.x); acc.y = fmaf(v4, bf_hi(g4), acc.y);
        acc.x = fmaf(v5, bf_lo(g5), acc.x); acc.y = fmaf(v5, bf_hi(g5), acc.y);
        acc.x = fmaf(v6, bf_lo(g6), acc.x); acc.y = fmaf(v6, bf_hi(g6), acc.y);
        acc.x = fmaf(v7, bf_lo(g7), acc.x); acc.y = fmaf(v7, bf_hi(g7), acc.y);
    }
    for (; i < deg; ++i) {
        int2 c = s[i];
        float v = __int_as_float(c.y);
        unsigned g = xb[(size_t)c.x * 64 + lane];
        acc.x = fmaf(v, bf_lo(g), acc.x);
        acc.y = fmaf(v, bf_hi(g), acc.y);
    }
    outb[(size_t)row * 64 + lane] = pack_bf2(acc.x, acc.y);
}

// ---------------------------------------------------------------- SpMM layers 2-3

__global__ __launch_bounds__(256) void spmm_kernel(
        const int* __restrict__ cnt, const int2* __restrict__ ell,
        const unsigned* __restrict__ xb,
        float* __restrict__ out32, unsigned* __restrict__ outb) {
    int row = blockIdx.x * 4 + (threadIdx.x >> 6);
    if (row >= N_TOTAL) return;
    int lane = threadIdx.x & 63;
    unsigned sw = xb[(size_t)row * 64 + lane];
    float2 acc;
    acc.x = ALPHA_F * bf_lo(sw);
    acc.y = ALPHA_F * bf_hi(sw);
    int deg = min(cnt[row], ELL_CAP);
    const int2* base = ell + (size_t)row * ELL_CAP;
    int i = 0;
    for (; i + 8 <= deg; i += 8) {
        int4 p0 = *reinterpret_cast<const int4*>(base + i);
        int4 p1 = *reinterpret_cast<const int4*>(base + i + 2);
        int4 p2 = *reinterpret_cast<const int4*>(base + i + 4);
        int4 p3 = *reinterpret_cast<const int4*>(base + i + 6);
        unsigned g0 = xb[(size_t)p0.x * 64 + lane];
        unsigned g1 = xb[(size_t)p0.z * 64 + lane];
        unsigned g2 = xb[(size_t)p1.x * 64 + lane];
        unsigned g3 = xb[(size_t)p1.z * 64 + lane];
        unsigned g4 = xb[(size_t)p2.x * 64 + lane];
        unsigned g5 = xb[(size_t)p2.z * 64 + lane];
        unsigned g6 = xb[(size_t)p3.x * 64 + lane];
        unsigned g7 = xb[(size_t)p3.z * 64 + lane];
        float v0 = __int_as_float(p0.y), v1 = __int_as_float(p0.w);
        float v2 = __int_as_float(p1.y), v3 = __int_as_float(p1.w);
        float v4 = __int_as_float(p2.y), v5 = __int_as_float(p2.w);
        float v6 = __int_as_float(p3.y), v7 = __int_as_float(p3.w);
        acc.x = fmaf(v0, bf_lo(g0), acc.x); acc.y = fmaf(v0, bf_hi(g0), acc.y);
        acc.x = fmaf(v1, bf_lo(g1), acc.x); acc.y = fmaf(v1, bf_hi(g1), acc.y);
        acc.x = fmaf(v2, bf_lo(g2), acc.x); acc.y = fmaf(v2, bf_hi(g2), acc.y);
        acc.x = fmaf(v3, bf_lo(g3), acc.x); acc.y = fmaf(v3, bf_hi(g3), acc.y);
        acc.x = fmaf(v4, bf_lo(g4), acc.x); acc.y = fmaf(v4, bf_hi(g4), acc.y);
        acc.x = fmaf(v5, bf_lo(g5), acc.x); acc.y = fmaf(v5, bf_hi(g5), acc.y);
        acc.x = fmaf(v6, bf_lo(g6), acc.x); acc.y = fmaf(v6, bf_hi(g6), acc.y);
        acc.x = fmaf(v7, bf_lo(g7), acc.x); acc.y = fmaf(v7, bf_hi(g7), acc.y);
    }
    for (; i < deg; ++i) {
        int2 c = base[i];
        float v = __int_as_float(c.y);
        unsigned g = xb[(size_t)c.x * 64 + lane];
        acc.x = fmaf(v, bf_lo(g), acc.x);
        acc.y = fmaf(v, bf_hi(g), acc.y);
    }
    if (out32) {
        out32[(size_t)row * 128 + lane] = acc.x;
        out32[(size_t)row * 128 + 64 + lane] = acc.y;
    }
    if (outb)
        outb[(size_t)row * 64 + lane] = pack_bf2(acc.x, acc.y);
}

// ---------------------------------------------------------------- launch

extern "C" void kernel_launch(void* const* d_in, const int* in_sizes, int n_in,
                              void* d_out, int out_size, void* d_ws, size_t ws_size,
                              hipStream_t stream) {
    const float* image_feats = (const float*)d_in[0];
    const float* text_feats  = (const float*)d_in[1];
    const float* image_pref  = (const float*)d_in[2];
    const float* text_pref   = (const float*)d_in[3];
    const float* W_img       = (const float*)d_in[4];
    const float* b_img       = (const float*)d_in[5];
    const float* W_txt       = (const float*)d_in[6];
    const float* b_txt       = (const float*)d_in[7];
    const float* adj_vals    = (const float*)d_in[8];
    const int*   adj_rows    = (const int*)d_in[9];
    const int*   adj_cols    = (const int*)d_in[10];

    float* out = (float*)d_out;                          // [150000*128]

    char* ws = (char*)d_ws;
    size_t off = 0;
    auto alloc = [&](size_t bytes) { char* p = ws + off; off += (bytes + 255) & ~size_t(255); return p; };
    int*      cnt   = (int*)     alloc(N_TOTAL * sizeof(int));
    int2*     ell   = (int2*)    alloc((size_t)N_TOTAL * ELL_CAP * sizeof(int2));
    unsigned* m0    = (unsigned*)alloc((size_t)N_TOTAL * 64 * sizeof(unsigned));
    unsigned* m1    = (unsigned*)alloc((size_t)N_TOTAL * 64 * sizeof(unsigned));
    char*     WtiT  = (char*)    alloc((size_t)NC_IMG * 8192);
    char*     WttT  = (char*)    alloc((size_t)6 * 8192);
    (void)ws_size; (void)out_size; (void)n_in; (void)in_sizes;

    // --- prep: zero cnt + tiled/swizzled bf16 B ---
    prep_kernel<<<512, 256, 0, stream>>>(W_img, W_txt, cnt, WtiT, WttT);

    // --- mega: scatter || copy || GEMM (16-row blocks, 24KB LDS, 6 blocks/CU) ---
    mega_kernel<<<G_PRE + G_GEMM, 256, 0, stream>>>(
        image_feats, text_feats, WtiT, WttT, b_img, b_txt, m0,
        adj_rows, adj_cols, adj_vals, cnt, ell, image_pref, text_pref);

    // --- layer 1 (+ canonical in-kernel sort), then layers 2-3 ---
    const int ROW_GRID = (N_TOTAL + 3) / 4;
    spmm_sort_kernel<<<ROW_GRID, 256, 0, stream>>>(cnt, ell, m0, m1);
    spmm_kernel<<<ROW_GRID, 256, 0, stream>>>(cnt, ell, m1, nullptr, m0);
    spmm_kernel<<<ROW_GRID, 256, 0, stream>>>(cnt, ell, m0, out, nullptr);
}

// Round 16
// 961.535 us; speedup vs baseline: 1.1269x; 1.0055x over previous
//
#include <hip/hip_runtime.h>
#include <hip/hip_bf16.h>

#define N_USERS 100000
#define N_ITEMS 50000
#define N_TOTAL 150000
#define NNZ     4000000
#define ALPHA_F 0.8f
#define ELL_CAP 128

#define G_SCAT 1024
#define G_COPY 128
#define G_PRE  (G_SCAT + G_COPY)
#define G_GEMM 3125           // N_ITEMS / 16 exactly
#define NC_IMG 64             // img chunks of K=64
#define NC_ALL 70             // + 6 txt chunks of K=64

typedef __attribute__((ext_vector_type(8))) short bf16x8;
typedef __attribute__((ext_vector_type(4))) float f32x4;

static __device__ __forceinline__ short f2bf(float f) {
    unsigned u = __builtin_bit_cast(unsigned, f);
    unsigned r = (u + 0x7fff + ((u >> 16) & 1)) >> 16;   // RTNE
    return (short)r;
}
static __device__ __forceinline__ unsigned pack_bf2(float a, float b) {
    return (unsigned)(unsigned short)f2bf(a) | ((unsigned)(unsigned short)f2bf(b) << 16);
}
static __device__ __forceinline__ float bf_lo(unsigned u) { return __uint_as_float(u << 16); }
static __device__ __forceinline__ float bf_hi(unsigned u) { return __uint_as_float(u & 0xFFFF0000u); }

static __device__ __forceinline__ void gload_lds16(const void* src, void* dst) {
    __builtin_amdgcn_global_load_lds(
        (const __attribute__((address_space(1))) unsigned*)src,
        (__attribute__((address_space(3))) unsigned*)dst, 16, 0, 0);
}

// ---------------------------------------------------------------- prep

__global__ __launch_bounds__(256) void prep_kernel(const float* __restrict__ Wimg,
                                                   const float* __restrict__ Wtxt,
                                                   int* __restrict__ cnt,
                                                   char* __restrict__ WtiT,
                                                   char* __restrict__ WttT) {
    const int T0 = N_TOTAL;
    const int T1 = T0 + 4096 * 64;
    const int T2 = T1 + 384 * 64;
    int i = blockIdx.x * 256 + threadIdx.x;
    int stride = gridDim.x * 256;
    for (; i < T2; i += stride) {
        if (i < T0) {
            cnt[i] = 0;
        } else if (i < T1) {
            int idx = i - T0; int k = idx >> 6, n = idx & 63;
            int c = k >> 6, kk = k & 63;
            *(short*)(WtiT + c * 8192 + n * 128 + ((kk * 2) ^ ((n & 7) << 4)))
                = f2bf(Wimg[(size_t)k * 64 + n]);
        } else {
            int idx = i - T1; int k = idx >> 6, n = idx & 63;
            int c = k >> 6, kk = k & 63;
            *(short*)(WttT + c * 8192 + n * 128 + ((kk * 2) ^ ((n & 7) << 4)))
                = f2bf(Wtxt[(size_t)k * 64 + n]);
        }
    }
}

// ---------------------------------------------------------------- mega kernel

__global__ __launch_bounds__(256, 6) void mega_kernel(
        const float* __restrict__ Aimg, const float* __restrict__ Atxt,
        const char* __restrict__ WtiT, const char* __restrict__ WttT,
        const float* __restrict__ bimg, const float* __restrict__ btxt,
        unsigned* __restrict__ egob,
        const int* __restrict__ rows, const int* __restrict__ cols,
        const float* __restrict__ vals, int* __restrict__ cnt, int2* __restrict__ ell,
        const float* __restrict__ img_pref, const float* __restrict__ txt_pref) {
    __shared__ __align__(16) char abuf[2][4096];
    __shared__ __align__(16) char bbuf[2][8192];
    int b = blockIdx.x;
    int t = threadIdx.x;
    int wave = t >> 6, lane = t & 63;

    if (b < G_SCAT) {
        int i = b * 256 + t;
        int stride = G_SCAT * 256;
        for (; i < NNZ; i += stride) {
            int r = rows[i];
            int p = atomicAdd(&cnt[r], 1);
            if (p < ELL_CAP)
                ell[(size_t)r * ELL_CAP + p] = make_int2(cols[i], __float_as_int(vals[i]));
        }
        return;
    }
    if (b < G_PRE) {
        int idx = (b - G_SCAT) * 256 + t;
        int stride = G_COPY * 256;
        for (; idx < N_USERS * 16; idx += stride) {
            int row = idx >> 4, w4 = (idx & 15) << 2;
            float4 iv = *reinterpret_cast<const float4*>(&img_pref[(size_t)row * 64 + w4]);
            float4 tv = *reinterpret_cast<const float4*>(&txt_pref[(size_t)row * 64 + w4]);
            uint4 m;
            m.x = pack_bf2(iv.x, tv.x); m.y = pack_bf2(iv.y, tv.y);
            m.z = pack_bf2(iv.z, tv.z); m.w = pack_bf2(iv.w, tv.w);
            *reinterpret_cast<uint4*>(&egob[(size_t)row * 64 + w4]) = m;
        }
        return;
    }

    const int blk = b - G_PRE;
    const int row0 = blk * 16;
    const int col = lane & 15, kb = lane >> 4;

    auto stage = [&](int ci, int bi) {
        const float* A; size_t rowbytes; const char* BT; int cc;
        if (ci < NC_IMG) { A = Aimg; rowbytes = 16384; BT = WtiT; cc = ci; }
        else             { A = Atxt; rowbytes = 1536;  BT = WttT; cc = ci - NC_IMG; }
        {
            int r = wave * 4 + (lane >> 4);
            int so = ((lane & 15) * 16) ^ ((r & 7) << 4);
            const char* src = (const char*)A + (size_t)(row0 + r) * rowbytes + cc * 256 + so;
            char* dst = abuf[bi] + wave * 1024 + lane * 16;
            gload_lds16(src, dst);
        }
        #pragma unroll
        for (int q = 0; q < 2; ++q) {
            int off = (q * 4 + wave) * 1024 + lane * 16;
            gload_lds16(BT + (size_t)cc * 8192 + off, bbuf[bi] + off);
        }
    };

    auto comp = [&](int bi, f32x4& acc) {
        const int r = col;
        const int aswz = (r & 7) << 4;
        const char* ab = abuf[bi] + r * 256;
        const int n = 16 * wave + col;
        const char* bb = bbuf[bi] + n * 128;
        const int bswz = (n & 7) << 4;
        #pragma unroll
        for (int ks = 0; ks < 2; ++ks) {
            int la = ks * 128 + kb * 32;
            float4 a0 = *(const float4*)(ab + (la ^ aswz));
            float4 a1 = *(const float4*)(ab + ((la + 16) ^ aswz));
            bf16x8 af;
            af[0]=f2bf(a0.x); af[1]=f2bf(a0.y); af[2]=f2bf(a0.z); af[3]=f2bf(a0.w);
            af[4]=f2bf(a1.x); af[5]=f2bf(a1.y); af[6]=f2bf(a1.z); af[7]=f2bf(a1.w);
            bf16x8 bf = *(const bf16x8*)(bb + ((ks * 64 + kb * 16) ^ bswz));
            acc = __builtin_amdgcn_mfma_f32_16x16x32_bf16(af, bf, acc, 0, 0, 0);
        }
    };

    f32x4 ai = {0.f,0.f,0.f,0.f}, at4 = {0.f,0.f,0.f,0.f};

    stage(0, 0);
    for (int ci = 0; ci < NC_ALL; ++ci) {
        int bi = ci & 1;
        if (ci + 1 < NC_ALL) {
            stage(ci + 1, bi ^ 1);
            asm volatile("s_waitcnt vmcnt(3)" ::: "memory");
        } else {
            asm volatile("s_waitcnt vmcnt(0)" ::: "memory");
        }
        __builtin_amdgcn_s_barrier();
        __builtin_amdgcn_sched_barrier(0);
        if (ci < NC_IMG) comp(bi, ai);
        else             comp(bi, at4);
        __builtin_amdgcn_sched_barrier(0);
        __builtin_amdgcn_s_barrier();
    }

    float bv_i = bimg[16 * wave + col];
    float bv_t = btxt[16 * wave + col];
    float ssi[4], sst[4];
    #pragma unroll
    for (int i = 0; i < 4; ++i) {
        ai[i] += bv_i; at4[i] += bv_t;
        ssi[i] = ai[i] * ai[i];
        sst[i] = at4[i] * at4[i];
    }
    #pragma unroll
    for (int off = 1; off < 16; off <<= 1) {
        #pragma unroll
        for (int i = 0; i < 4; ++i) {
            ssi[i] += __shfl_xor(ssi[i], off, 64);
            sst[i] += __shfl_xor(sst[i], off, 64);
        }
    }
    float* S = (float*)abuf;
    __syncthreads();
    if (col == 0) {
        #pragma unroll
        for (int i = 0; i < 4; ++i) {
            S[wave * 16 + kb * 4 + i]      = ssi[i];
            S[64 + wave * 16 + kb * 4 + i] = sst[i];
        }
    }
    __syncthreads();
    unsigned* egob_items = egob + (size_t)N_USERS * 64;
    #pragma unroll
    for (int i = 0; i < 4; ++i) {
        int r = kb * 4 + i;
        float ti = S[r] + S[16 + r] + S[32 + r] + S[48 + r];
        float tt = S[64 + r] + S[80 + r] + S[96 + r] + S[112 + r];
        float rni = 1.0f / fmaxf(sqrtf(ti), 1e-12f);
        float rnt = 1.0f / fmaxf(sqrtf(tt), 1e-12f);
        egob_items[(size_t)(row0 + r) * 64 + 16 * wave + col] =
            pack_bf2(ai[i] * rni, at4[i] * rnt);
    }
}

// ---------------------------------------------------------------- SpMM layer 1 + fused sort

__global__ __launch_bounds__(256) void spmm_sort_kernel(
        const int* __restrict__ cnt, int2* __restrict__ ell,
        const unsigned* __restrict__ xb, unsigned* __restrict__ outb) {
    __shared__ __align__(16) int2 srt[4][ELL_CAP];
    int wid = threadIdx.x >> 6, lane = threadIdx.x & 63;
    int row = blockIdx.x * 4 + wid;
    bool valid = row < N_TOTAL;
    int deg = 0;
    int2* base = nullptr;
    int2 e0 = make_int2(0x7FFFFFFF, 0), e1 = e0;
    if (valid) {
        deg = min(cnt[row], ELL_CAP);
        base = ell + (size_t)row * ELL_CAP;
        if (lane < deg)      e0 = base[lane];
        if (lane + 64 < deg) e1 = base[lane + 64];
    }
    #pragma unroll
    for (int k = 2; k <= 128; k <<= 1) {
        #pragma unroll
        for (int j = 64; j >= 1; j >>= 1) {
            if (j >= k) continue;
            if (j == 64) {
                if (e0.x > e1.x) { int2 tmp = e0; e0 = e1; e1 = tmp; }
            } else {
                int2 p0, p1;
                p0.x = __shfl_xor(e0.x, j, 64); p0.y = __shfl_xor(e0.y, j, 64);
                p1.x = __shfl_xor(e1.x, j, 64); p1.y = __shfl_xor(e1.y, j, 64);
                bool up0 = ((lane & k) == 0);
                bool up1 = (((lane + 64) & k) == 0);
                bool lo0 = ((lane & j) == 0);
                bool keepmin0 = (up0 == lo0);
                bool keepmin1 = (up1 == lo0);
                if (keepmin0 ? (e0.x > p0.x) : (e0.x < p0.x)) e0 = p0;
                if (keepmin1 ? (e1.x > p1.x) : (e1.x < p1.x)) e1 = p1;
            }
        }
    }
    if (valid) {
        if (lane < deg)      base[lane]      = e0;
        if (lane + 64 < deg) base[lane + 64] = e1;
    }
    srt[wid][lane] = e0;
    srt[wid][lane + 64] = e1;
    __syncthreads();
    if (!valid) return;
    unsigned sw = xb[(size_t)row * 64 + lane];
    float2 acc;
    acc.x = ALPHA_F * bf_lo(sw);
    acc.y = ALPHA_F * bf_hi(sw);
    const int2* s = srt[wid];
    int i = 0;
    for (; i + 8 <= deg; i += 8) {
        int4 p0 = *reinterpret_cast<const int4*>(s + i);
        int4 p1 = *reinterpret_cast<const int4*>(s + i + 2);
        int4 p2 = *reinterpret_cast<const int4*>(s + i + 4);
        int4 p3 = *reinterpret_cast<const int4*>(s + i + 6);
        unsigned g0 = xb[(size_t)p0.x * 64 + lane];
        unsigned g1 = xb[(size_t)p0.z * 64 + lane];
        unsigned g2 = xb[(size_t)p1.x * 64 + lane];
        unsigned g3 = xb[(size_t)p1.z * 64 + lane];
        unsigned g4 = xb[(size_t)p2.x * 64 + lane];
        unsigned g5 = xb[(size_t)p2.z * 64 + lane];
        unsigned g6 = xb[(size_t)p3.x * 64 + lane];
        unsigned g7 = xb[(size_t)p3.z * 64 + lane];
        float v0 = __int_as_float(p0.y), v1 = __int_as_float(p0.w);
        float v2 = __int_as_float(p1.y), v3 = __int_as_float(p1.w);
        float v4 = __int_as_float(p2.y), v5 = __int_as_float(p2.w);
        float v6 = __int_as_float(p3.y), v7 = __int_as_float(p3.w);
        acc.x = fmaf(v0, bf_lo(g0), acc.x); acc.y = fmaf(v0, bf_hi(g0), acc.y);
        acc.x = fmaf(v1, bf_lo(g1), acc.x); acc.y = fmaf(v1, bf_hi(g1), acc.y);
        acc.x = fmaf(v2, bf_lo(g2), acc.x); acc.y = fmaf(v2, bf_hi(g2), acc.y);
        acc.x = fmaf(v3, bf_lo(g3), acc.x); acc.y = fmaf(v3, bf_hi(g3), acc.y);
        acc.x = fmaf(v4, bf_lo(g4), acc.x); acc.y = fmaf(v4, bf_hi(g4), acc.y);
        acc.x = fmaf(v5, bf_lo(g5), acc.x); acc.y = fmaf(v5, bf_hi(g5), acc.y);
        acc.x = fmaf(v6, bf_lo(g6), acc.x); acc.y = fmaf(v6, bf_hi(g6), acc.y);
        acc.x = fmaf(v7, bf_lo(g7), acc.x); acc.y = fmaf(v7, bf_hi(g7), acc.y);
    }
    for (; i < deg; ++i) {
        int2 c = s[i];
        float v = __int_as_float(c.y);
        unsigned g = xb[(size_t)c.x * 64 + lane];
        acc.x = fmaf(v, bf_lo(g), acc.x);
        acc.y = fmaf(v, bf_hi(g), acc.y);
    }
    outb[(size_t)row * 64 + lane] = pack_bf2(acc.x, acc.y);
}

// ---------------------------------------------------------------- SpMM layers 2-3
// 2 rows per wave, 8 edges each in flight (16 gathers + 8 int4 ELL loads).
// Masked slots (col=0, val=0): fmaf(0,x,acc)==acc exactly -> bit-identical sums.

__global__ __launch_bounds__(256) void spmm2_kernel(
        const int* __restrict__ cnt, const int2* __restrict__ ell,
        const unsigned* __restrict__ xb,
        float* __restrict__ out32, unsigned* __restrict__ outb) {
    int wid = threadIdx.x >> 6, lane = threadIdx.x & 63;
    int rowA = blockIdx.x * 8 + wid * 2;     // N_TOTAL % 8 == 0: always valid
    int rowB = rowA + 1;
    int degA = min(cnt[rowA], ELL_CAP);
    int degB = min(cnt[rowB], ELL_CAP);
    const int2* baseA = ell + (size_t)rowA * ELL_CAP;
    const int2* baseB = ell + (size_t)rowB * ELL_CAP;
    unsigned swA = xb[(size_t)rowA * 64 + lane];
    unsigned swB = xb[(size_t)rowB * 64 + lane];
    float2 accA, accB;
    accA.x = ALPHA_F * bf_lo(swA); accA.y = ALPHA_F * bf_hi(swA);
    accB.x = ALPHA_F * bf_lo(swB); accB.y = ALPHA_F * bf_hi(swB);
    int dmax = max(degA, degB);
    for (int i = 0; i < dmax; i += 8) {
        int4 pa0 = *reinterpret_cast<const int4*>(baseA + i);
        int4 pa1 = *reinterpret_cast<const int4*>(baseA + i + 2);
        int4 pa2 = *reinterpret_cast<const int4*>(baseA + i + 4);
        int4 pa3 = *reinterpret_cast<const int4*>(baseA + i + 6);
        int4 pb0 = *reinterpret_cast<const int4*>(baseB + i);
        int4 pb1 = *reinterpret_cast<const int4*>(baseB + i + 2);
        int4 pb2 = *reinterpret_cast<const int4*>(baseB + i + 4);
        int4 pb3 = *reinterpret_cast<const int4*>(baseB + i + 6);
        int ca0 = (i+0<degA)?pa0.x:0; float va0 = (i+0<degA)?__int_as_float(pa0.y):0.f;
        int ca1 = (i+1<degA)?pa0.z:0; float va1 = (i+1<degA)?__int_as_float(pa0.w):0.f;
        int ca2 = (i+2<degA)?pa1.x:0; float va2 = (i+2<degA)?__int_as_float(pa1.y):0.f;
        int ca3 = (i+3<degA)?pa1.z:0; float va3 = (i+3<degA)?__int_as_float(pa1.w):0.f;
        int ca4 = (i+4<degA)?pa2.x:0; float va4 = (i+4<degA)?__int_as_float(pa2.y):0.f;
        int ca5 = (i+5<degA)?pa2.z:0; float va5 = (i+5<degA)?__int_as_float(pa2.w):0.f;
        int ca6 = (i+6<degA)?pa3.x:0; float va6 = (i+6<degA)?__int_as_float(pa3.y):0.f;
        int ca7 = (i+7<degA)?pa3.z:0; float va7 = (i+7<degA)?__int_as_float(pa3.w):0.f;
        int cb0 = (i+0<degB)?pb0.x:0; float vb0 = (i+0<degB)?__int_as_float(pb0.y):0.f;
        int cb1 = (i+1<degB)?pb0.z:0; float vb1 = (i+1<degB)?__int_as_float(pb0.w):0.f;
        int cb2 = (i+2<degB)?pb1.x:0; float vb2 = (i+2<degB)?__int_as_float(pb1.y):0.f;
        int cb3 = (i+3<degB)?pb1.z:0; float vb3 = (i+3<degB)?__int_as_float(pb1.w):0.f;
        int cb4 = (i+4<degB)?pb2.x:0; float vb4 = (i+4<degB)?__int_as_float(pb2.y):0.f;
        int cb5 = (i+5<degB)?pb2.z:0; float vb5 = (i+5<degB)?__int_as_float(pb2.w):0.f;
        int cb6 = (i+6<degB)?pb3.x:0; float vb6 = (i+6<degB)?__int_as_float(pb3.y):0.f;
        int cb7 = (i+7<degB)?pb3.z:0; float vb7 = (i+7<degB)?__int_as_float(pb3.w):0.f;
        unsigned ga0 = xb[(size_t)ca0 * 64 + lane];
        unsigned ga1 = xb[(size_t)ca1 * 64 + lane];
        unsigned ga2 = xb[(size_t)ca2 * 64 + lane];
        unsigned ga3 = xb[(size_t)ca3 * 64 + lane];
        unsigned ga4 = xb[(size_t)ca4 * 64 + lane];
        unsigned ga5 = xb[(size_t)ca5 * 64 + lane];
        unsigned ga6 = xb[(size_t)ca6 * 64 + lane];
        unsigned ga7 = xb[(size_t)ca7 * 64 + lane];
        unsigned gb0 = xb[(size_t)cb0 * 64 + lane];
        unsigned gb1 = xb[(size_t)cb1 * 64 + lane];
        unsigned gb2 = xb[(size_t)cb2 * 64 + lane];
        unsigned gb3 = xb[(size_t)cb3 * 64 + lane];
        unsigned gb4 = xb[(size_t)cb4 * 64 + lane];
        unsigned gb5 = xb[(size_t)cb5 * 64 + lane];
        unsigned gb6 = xb[(size_t)cb6 * 64 + lane];
        unsigned gb7 = xb[(size_t)cb7 * 64 + lane];
        accA.x = fmaf(va0, bf_lo(ga0), accA.x); accA.y = fmaf(va0, bf_hi(ga0), accA.y);
        accA.x = fmaf(va1, bf_lo(ga1), accA.x); accA.y = fmaf(va1, bf_hi(ga1), accA.y);
        accA.x = fmaf(va2, bf_lo(ga2), accA.x); accA.y = fmaf(va2, bf_hi(ga2), accA.y);
        accA.x = fmaf(va3, bf_lo(ga3), accA.x); accA.y = fmaf(va3, bf_hi(ga3), accA.y);
        accA.x = fmaf(va4, bf_lo(ga4), accA.x); accA.y = fmaf(va4, bf_hi(ga4), accA.y);
        accA.x = fmaf(va5, bf_lo(ga5), accA.x); accA.y = fmaf(va5, bf_hi(ga5), accA.y);
        accA.x = fmaf(va6, bf_lo(ga6), accA.x); accA.y = fmaf(va6, bf_hi(ga6), accA.y);
        accA.x = fmaf(va7, bf_lo(ga7), accA.x); accA.y = fmaf(va7, bf_hi(ga7), accA.y);
        accB.x = fmaf(vb0, bf_lo(gb0), accB.x); accB.y = fmaf(vb0, bf_hi(gb0), accB.y);
        accB.x = fmaf(vb1, bf_lo(gb1), accB.x); accB.y = fmaf(vb1, bf_hi(gb1), accB.y);
        accB.x = fmaf(vb2, bf_lo(gb2), accB.x); accB.y = fmaf(vb2, bf_hi(gb2), accB.y);
        accB.x = fmaf(vb3, bf_lo(gb3), accB.x); accB.y = fmaf(vb3, bf_hi(gb3), accB.y);
        accB.x = fmaf(vb4, bf_lo(gb4), accB.x); accB.y = fmaf(vb4, bf_hi(gb4), accB.y);
        accB.x = fmaf(vb5, bf_lo(gb5), accB.x); accB.y = fmaf(vb5, bf_hi(gb5), accB.y);
        accB.x = fmaf(vb6, bf_lo(gb6), accB.x); accB.y = fmaf(vb6, bf_hi(gb6), accB.y);
        accB.x = fmaf(vb7, bf_lo(gb7), accB.x); accB.y = fmaf(vb7, bf_hi(gb7), accB.y);
    }
    if (out32) {
        out32[(size_t)rowA * 128 + lane] = accA.x;
        out32[(size_t)rowA * 128 + 64 + lane] = accA.y;
        out32[(size_t)rowB * 128 + lane] = accB.x;
        out32[(size_t)rowB * 128 + 64 + lane] = accB.y;
    }
    if (outb) {
        outb[(size_t)rowA * 64 + lane] = pack_bf2(accA.x, accA.y);
        outb[(size_t)rowB * 64 + lane] = pack_bf2(accB.x, accB.y);
    }
}

// ---------------------------------------------------------------- launch

extern "C" void kernel_launch(void* const* d_in, const int* in_sizes, int n_in,
                              void* d_out, int out_size, void* d_ws, size_t ws_size,
                              hipStream_t stream) {
    const float* image_feats = (const float*)d_in[0];
    const float* text_feats  = (const float*)d_in[1];
    const float* image_pref  = (const float*)d_in[2];
    const float* text_pref   = (const float*)d_in[3];
    const float* W_img       = (const float*)d_in[4];
    const float* b_img       = (const float*)d_in[5];
    const float* W_txt       = (const float*)d_in[6];
    const float* b_txt       = (const float*)d_in[7];
    const float* adj_vals    = (const float*)d_in[8];
    const int*   adj_rows    = (const int*)d_in[9];
    const int*   adj_cols    = (const int*)d_in[10];

    float* out = (float*)d_out;                          // [150000*128]

    char* ws = (char*)d_ws;
    size_t off = 0;
    auto alloc = [&](size_t bytes) { char* p = ws + off; off += (bytes + 255) & ~size_t(255); return p; };
    int*      cnt   = (int*)     alloc(N_TOTAL * sizeof(int));
    int2*     ell   = (int2*)    alloc((size_t)N_TOTAL * ELL_CAP * sizeof(int2));
    unsigned* m0    = (unsigned*)alloc((size_t)N_TOTAL * 64 * sizeof(unsigned));
    unsigned* m1    = (unsigned*)alloc((size_t)N_TOTAL * 64 * sizeof(unsigned));
    char*     WtiT  = (char*)    alloc((size_t)NC_IMG * 8192);
    char*     WttT  = (char*)    alloc((size_t)6 * 8192);
    (void)ws_size; (void)out_size; (void)n_in; (void)in_sizes;

    // --- prep: zero cnt + tiled/swizzled bf16 B ---
    prep_kernel<<<512, 256, 0, stream>>>(W_img, W_txt, cnt, WtiT, WttT);

    // --- mega: scatter || copy || GEMM (R15 structure, frozen) ---
    mega_kernel<<<G_PRE + G_GEMM, 256, 0, stream>>>(
        image_feats, text_feats, WtiT, WttT, b_img, b_txt, m0,
        adj_rows, adj_cols, adj_vals, cnt, ell, image_pref, text_pref);

    // --- layer 1 (+ canonical in-kernel sort), then layers 2-3 (2-row MLP) ---
    const int ROW_GRID4 = (N_TOTAL + 3) / 4;
    const int ROW_GRID8 = N_TOTAL / 8;
    spmm_sort_kernel<<<ROW_GRID4, 256, 0, stream>>>(cnt, ell, m0, m1);
    spmm2_kernel<<<ROW_GRID8, 256, 0, stream>>>(cnt, ell, m1, nullptr, m0);
    spmm2_kernel<<<ROW_GRID8, 256, 0, stream>>>(cnt, ell, m0, out, nullptr);
}